// Round 9
// baseline (281.198 us; speedup 1.0000x reference)
//
#include <hip/hip_runtime.h>
#include <hip/hip_fp16.h>

// SiameseEdgeConvNet: 2-layer EdgeConv (max aggr) on two graphs, shared weights.
// N=50000, E=1.6e6, dims 32 -> 64 -> 64.
//
// Algebra: msg = relu([xi, xj-xi] @ W + b) = relu(xi@A + xj@B + b),
//   A=W_lo-W_hi, B=W_hi.  u = x@A + b, v = x@B per node; ReLU monotone =>
//   out[d] = relu(u[d] + max_{e: dst=d} v[src_e]);  empty segment -> 0.
//   PReLU input >= 0 -> identity -> skipped.
//
// R21. Ledger (do NOT retry):
//   - R13 per-node global binning: 250 us (random 2B stores, 186 MB writes).
//   - R15 temporal half-row agg passes: FETCH 114->168 MB.
//   - R16 2 agg blocks/bucket (node halves): duplicate record scan, 55 us.
//   - R17 spatial CHANNEL-half x XCD: 64B half-gathers still pull full HBM
//     sectors from 2 XCDs -> vk HBM 2x, FETCH 195 MB, 86 us.
//   - R18 bin short runs (1.3 rec): 68 us despite occ 2x. Bin tracks RUN
//     LENGTH: {1.3 rec -> 68} {2.6 -> 47.7} {5.2 -> <53} {10.5 -> <59}.
//   - R19/R20 agg occupancy scan: dur tracks resident waves at fixed
//     FETCH~114MB, but ceiling is ~30 GB/s/CU random-gather = MSHR
//     saturation: throughput = miss-slots x 64B / avg-latency (~340cyc,
//     14% HBM misses at 900cyc).
// R21: cut avg latency via SRC-PARITY split (src&1), one (graph,half) per
//   XCD pair -> per-XCD gather set = 3.2 MB < 4 MB L2 -> all-L2 latency.
//   Rows gathered WHOLE by one XCD pair (no R17 sector split); bin buckets
//   keyed (dst>>7)*2|(src&1) -> single scan per block (no R16 dup), bucket
//   count/graph unchanged (782) -> bin run length unchanged (5.2).
//   Half-merge via relu monotonicity:
//     L1: agg writes q_sh = rn16(relu(u+max_sh)); h = max(q0,q1) (max
//         commutes with RN rounding -> bit-identical to unsplit). gemm64
//         fuses the max into its A-load (8 v_pk_max_f16, +16B/lane).
//     L2: agg writes raw fp16 partial max (-inf when empty, automatic);
//         merge kernel: out = relu(u + h2f(pkmax(p0,p1))) fp32 (exact).

constexpr int HID   = 64;
constexpr int TILE  = 128;          // dst nodes per bucket (dst >> 7)
constexpr int TSH   = 7;            // log2(TILE)
constexpr int CAP   = 2560;         // records per bucket (mean 2046, +11s)
constexpr int MAXNB = 1024;         // max buckets = 2*ceil(65536/128)
constexpr int EPT   = 4;            // edges per thread in bin_kernel (1024t)
constexpr int CAPN  = 48;           // per-(node,half) cap (mean 16, max ~36)

typedef _Float16 half8 __attribute__((ext_vector_type(8)));
typedef float    f32x4 __attribute__((ext_vector_type(4)));

__device__ __forceinline__ unsigned int pkmax(unsigned int a, unsigned int b) {
    unsigned int d;
    asm("v_pk_max_f16 %0, %1, %2" : "=v"(d) : "v"(a), "v"(b));
    return d;
}
__device__ __forceinline__ unsigned short f2hbits(float f) {
    const __half h = __float2half_rn(f);
    return *reinterpret_cast<const unsigned short*>(&h);
}
__device__ __forceinline__ float h2f(unsigned int b16) {
    const unsigned short b = (unsigned short)b16;
    __half h;
    *reinterpret_cast<unsigned short*>(&h) = b;
    return __half2float(h);
}

struct G {                    // one graph's pointer set
    const float* x;           // [N,32] layer-1 input
    const int*   src;         // [E]
    const int*   dst;         // [E]
    int* bcnt;                // [2*NBD]    bucket fill counters
    unsigned int* bin;        // [2*NBD*CAP] packed records (src<<7 | dst&127)
    float*          u;        // [N,64] fp32
    unsigned short* vk;       // [(N+1),64] fp16, permuted: uint2 slot m of a
                              //   row holds channels {m,m+16,m+32,m+48};
                              //   row N = -inf sentinel (set once in prep_w)
    unsigned short* q;        // [2][N,64] fp16 row-major — per-src-half
                              //   partials (L1: relu(u+max); L2: raw max)
    float*          out;      // [N,64] fp32 — final output
};

// ---- weight prep + vk sentinel row init ----
__global__ __launch_bounds__(256) void prep_w_kernel(
    const float* __restrict__ W1, const float* __restrict__ W2,
    _Float16* __restrict__ Wc1, _Float16* __restrict__ Wc2,
    unsigned short* __restrict__ vkS0, unsigned short* __restrict__ vkS1, int N)
{
    const int i = blockIdx.x * 256 + threadIdx.x;
    if (i < 32 * 64) {
        const int k = i >> 6, c = i & 63;
        const float lo = W1[k * 64 + c], hi = W1[(32 + k) * 64 + c];
        Wc1[k * 128 + c]      = (_Float16)(lo - hi);
        Wc1[k * 128 + 64 + c] = (_Float16)hi;
    }
    const int j = i - 32 * 64;
    if (j >= 0 && j < 64 * 64) {
        const int k = j >> 6, c = j & 63;
        const float lo = W2[k * 64 + c], hi = W2[(64 + k) * 64 + c];
        Wc2[k * 128 + c]      = (_Float16)(lo - hi);
        Wc2[k * 128 + 64 + c] = (_Float16)hi;
    }
    const int q = i - (32 * 64 + 64 * 64);
    if (q >= 0 && q < 2 * HID) {                 // sentinel rows = -inf fp16
        if (q < HID) vkS0[(size_t)N * HID + q]       = 0xFC00u;
        else         vkS1[(size_t)N * HID + (q-HID)] = 0xFC00u;
    }
}

// ---- bin: block-reserved capacity scatter, 1024 threads ----
// bucket = (dst>>7)*2 | (src&1): src-parity split keeps per-bucket runs at
// ~5.2 records (edges/block 4096 over 782 buckets) — the proven-fast regime.
__global__ __launch_bounds__(1024) void bin_kernel(G g0, G g1, int E, int NB) {
    const G g = blockIdx.y ? g1 : g0;
    __shared__ int lh[MAXNB];   // local hist, then local write offset
    __shared__ int lb[MAXNB];   // reserved base per bucket
    for (int i = threadIdx.x; i < NB; i += 1024) lh[i] = 0;
    __syncthreads();

    const int base = blockIdx.x * 1024 * EPT;
    unsigned int rec[EPT];
    int bb[EPT];
    #pragma unroll
    for (int k = 0; k < EPT; ++k) {
        const int i = base + k * 1024 + threadIdx.x;   // coalesced stream
        if (i < E) {
            const int d = g.dst[i];
            const int s = g.src[i];
            rec[k] = ((unsigned int)s << TSH) | (unsigned int)(d & (TILE - 1));
            bb[k]  = ((d >> TSH) << 1) | (s & 1);
            atomicAdd(&lh[bb[k]], 1);
        } else bb[k] = -1;
    }
    __syncthreads();
    for (int t = threadIdx.x; t < NB; t += 1024) {
        const int c = lh[t];
        lb[t] = c ? atomicAdd(&g.bcnt[t], c) : 0;   // global range reservation
        lh[t] = 0;
    }
    __syncthreads();
    #pragma unroll
    for (int k = 0; k < EPT; ++k) {
        if (bb[k] >= 0) {
            const int off = atomicAdd(&lh[bb[k]], 1);
            const int pos = lb[bb[k]] + off;
            if (pos < CAP)                            // 11-sigma guard
                g.bin[(size_t)bb[k] * CAP + pos] = rec[k];
        }
    }
}

// ---- MFMA node GEMM: [u|v](N x 128) = in(N x K) @ Wc(K x 128); u += bias ----
// MODE 0: input = g.x fp32.  MODE 1 (K=64): input = max(q0,q1) fp16 — the
// src-half merge fused into the A-load via v_pk_max_f16 (relu-monotone).
// v emitted as raw fp16, permuted: uint2 slot m holds ch {m,m+16,m+32,m+48}.
template<int K, int MODE>
__global__ __launch_bounds__(256) void gemm_mfma_kernel(
    G g0, G g1, const _Float16* __restrict__ Wc,
    const float* __restrict__ bias, int N)
{
    const G g = blockIdx.y ? g1 : g0;
    constexpr int KH = K / 32;                 // k-halves (1 or 2)
    const int lane = threadIdx.x & 63;
    const int m    = lane & 15;                // A row / D col-lane
    const int quad = lane >> 4;
    const int wid  = (blockIdx.x * 256 + threadIdx.x) >> 6;
    const int nW   = (gridDim.x * 256) >> 6;

    // B-frags: B[k=32h+quad*8+j][n=16t+m]
    half8 bf[8][KH];
    #pragma unroll
    for (int t = 0; t < 8; ++t)
        #pragma unroll
        for (int hh = 0; hh < KH; ++hh)
            #pragma unroll
            for (int j = 0; j < 8; ++j)
                bf[t][hh][j] = Wc[(hh * 32 + quad * 8 + j) * 128 + t * 16 + m];

    float bv[4];
    #pragma unroll
    for (int t = 0; t < 4; ++t) bv[t] = bias[t * 16 + m];

    const int tiles = (N + 15) / 16;

    for (int tile = wid; tile < tiles; tile += nW) {
        const int nbase = tile * 16;
        const int nodeA = min(nbase + m, N - 1);

        half8 a[KH];
        if constexpr (MODE == 1) {
            const unsigned short* q0r = g.q + (size_t)nodeA * HID;
            const unsigned short* q1r = q0r + (size_t)N * HID;
            #pragma unroll
            for (int hh = 0; hh < KH; ++hh) {
                const int cb = hh * 32 + quad * 8;
                const uint4 a0 = *(const uint4*)(q0r + cb);
                const uint4 a1 = *(const uint4*)(q1r + cb);
                uint4 rr;
                rr.x = pkmax(a0.x, a1.x);
                rr.y = pkmax(a0.y, a1.y);
                rr.z = pkmax(a0.z, a1.z);
                rr.w = pkmax(a0.w, a1.w);
                a[hh] = *reinterpret_cast<half8*>(&rr);
            }
        } else {
            const float4* rp = (const float4*)(g.x + (size_t)nodeA * K);
            #pragma unroll
            for (int hh = 0; hh < KH; ++hh) {
                const float4 f0 = rp[hh * 8 + quad * 2];
                const float4 f1 = rp[hh * 8 + quad * 2 + 1];
                a[hh][0] = (_Float16)f0.x; a[hh][1] = (_Float16)f0.y;
                a[hh][2] = (_Float16)f0.z; a[hh][3] = (_Float16)f0.w;
                a[hh][4] = (_Float16)f1.x; a[hh][5] = (_Float16)f1.y;
                a[hh][6] = (_Float16)f1.z; a[hh][7] = (_Float16)f1.w;
            }
        }

        f32x4 acc[8];
        #pragma unroll
        for (int t = 0; t < 8; ++t) {
            acc[t] = (f32x4){0.f, 0.f, 0.f, 0.f};
            #pragma unroll
            for (int hh = 0; hh < KH; ++hh)
                acc[t] = __builtin_amdgcn_mfma_f32_16x16x32_f16(
                    a[hh], bf[t][hh], acc[t], 0, 0, 0);
        }

        // D[m=quad*4+r][n=lane&15]
        #pragma unroll
        for (int r = 0; r < 4; ++r) {
            const int node = nbase + quad * 4 + r;
            if (node < N) {
                float* urow = g.u + (size_t)node * HID;
                #pragma unroll
                for (int t = 0; t < 4; ++t)
                    urow[t * 16 + m] = acc[t][r] + bv[t];
                const unsigned int e0 = f2hbits(acc[4][r]);   // channel m
                const unsigned int e1 = f2hbits(acc[5][r]);   // channel m+16
                const unsigned int e2 = f2hbits(acc[6][r]);   // channel m+32
                const unsigned int e3 = f2hbits(acc[7][r]);   // channel m+48
                uint2 pack;
                pack.x = (e1 << 16) | e0;
                pack.y = (e3 << 16) | e2;
                ((uint2*)(g.vk + (size_t)node * HID))[m] = pack;
            }
        }
    }
}

// ---- aggregate: block = (128-dst-node bucket, src-half) ----
// XCD partition (two=1): xcd=bid&7 -> graph=xcd>>2, src-half=(xcd>>1)&1.
// Each XCD gathers only vk rows with src&1==sh: 3.2 MB -> L2-resident.
// Phase A: SINGLE scan of this (bucket,half)'s records, counting sort into
//   lrec[128][48], sentinel-pad x16 (src=N -> -inf row).
// Phase B: 16 groups x 16 lanes, 8 sequential nodes; full-row uint2 gathers,
//   16 in flight, v_pk_max_f16 accumulate.
// QOUT=1 (layer 1): store q_sh = rn16(relu(u+max)) (empty -> 0 automatic).
// QOUT=0 (layer 2): store raw fp16 max bits (empty -> -inf automatic).
template<int QOUT>
__global__ __launch_bounds__(256) void agg_kernel(G g0, G g1, int N, int NBD, int two) {
    int dstb, sh, gi;
    if (two) {
        const int bid = blockIdx.x;
        const int xcd = bid & 7;
        gi   = xcd >> 2;             // XCD 0-3: graph 0, XCD 4-7: graph 1
        sh   = (xcd >> 1) & 1;       // src-half
        dstb = (bid >> 3) * 2 + (xcd & 1);
    } else { gi = 0; dstb = blockIdx.x >> 1; sh = blockIdx.x & 1; }
    if (dstb >= NBD) return;
    const G g = gi ? g1 : g0;
    const int b = dstb * 2 + sh;     // bin bucket

    __shared__ int lcnt[TILE];
    __shared__ alignas(16) unsigned short lrec[TILE][CAPN];  // 12.3 KB
    for (int i = threadIdx.x; i < TILE; i += 256) lcnt[i] = 0;
    __syncthreads();

    const int cnt = min(g.bcnt[b], CAP);
    const unsigned int* __restrict__ bp = g.bin + (size_t)b * CAP;
    for (int i = threadIdx.x; i < cnt; i += 256) {
        const unsigned int rec = bp[i];
        const int d = rec & (TILE - 1);
        const int p = atomicAdd(&lcnt[d], 1);
        if (p < CAPN) lrec[d][p] = (unsigned short)(rec >> TSH);
    }
    __syncthreads();
    for (int t = threadIdx.x; t < TILE; t += 256) {   // pad to x16 w/ sentinel
        const int c  = min(lcnt[t], CAPN);
        const int cp = (c + 15) & ~15;
        for (int p = c; p < cp; ++p) lrec[t][p] = (unsigned short)N;
        lcnt[t] = cp;
    }
    __syncthreads();

    const int grp = threadIdx.x >> 4;        // 16 groups of 16 lanes
    const int sub = threadIdx.x & 15;
    const uint2* __restrict__ vk2 = (const uint2*)g.vk;
    unsigned short* __restrict__ qh = g.q + (size_t)sh * N * HID;

    #pragma unroll
    for (int i = 0; i < 8; ++i) {            // 8 sequential nodes per group
        const int nl = grp + 16 * i;
        const int n  = dstb * TILE + nl;
        if (n >= N) continue;
        const int cp = lcnt[nl];

        unsigned int m0 = 0xFC00FC00u, m1 = 0xFC00FC00u;   // -inf halves
        for (int j = 0; j < cp; j += 16) {
            const uint4 q0 = *(const uint4*)(&lrec[nl][j]);      // 16 recs,
            const uint4 q1 = *(const uint4*)(&lrec[nl][j + 8]);  // bcast
            unsigned int s[16];
            s[0]  = q0.x & 0xFFFFu; s[1]  = q0.x >> 16;
            s[2]  = q0.y & 0xFFFFu; s[3]  = q0.y >> 16;
            s[4]  = q0.z & 0xFFFFu; s[5]  = q0.z >> 16;
            s[6]  = q0.w & 0xFFFFu; s[7]  = q0.w >> 16;
            s[8]  = q1.x & 0xFFFFu; s[9]  = q1.x >> 16;
            s[10] = q1.y & 0xFFFFu; s[11] = q1.y >> 16;
            s[12] = q1.z & 0xFFFFu; s[13] = q1.z >> 16;
            s[14] = q1.w & 0xFFFFu; s[15] = q1.w >> 16;
            uint2 a[16];
            #pragma unroll
            for (int k = 0; k < 16; ++k) a[k] = vk2[(size_t)s[k] * 16 + sub];
            #pragma unroll
            for (int k = 0; k < 16; ++k) {
                m0 = pkmax(m0, a[k].x);
                m1 = pkmax(m1, a[k].y);
            }
        }

        unsigned short* prow = qh + (size_t)n * HID;
        if constexpr (QOUT) {        // L1: relu(u+max); u + (-inf) -> 0
            const float* __restrict__ urow = g.u + (size_t)n * HID;
            prow[sub]      = f2hbits(fmaxf(urow[sub]      + h2f(m0 & 0xFFFFu), 0.f));
            prow[sub + 16] = f2hbits(fmaxf(urow[sub + 16] + h2f(m0 >> 16),     0.f));
            prow[sub + 32] = f2hbits(fmaxf(urow[sub + 32] + h2f(m1 & 0xFFFFu), 0.f));
            prow[sub + 48] = f2hbits(fmaxf(urow[sub + 48] + h2f(m1 >> 16),     0.f));
        } else {                     // L2: raw partial max bits
            prow[sub]      = (unsigned short)(m0 & 0xFFFFu);
            prow[sub + 16] = (unsigned short)(m0 >> 16);
            prow[sub + 32] = (unsigned short)(m1 & 0xFFFFu);
            prow[sub + 48] = (unsigned short)(m1 >> 16);
        }
    }
}

// ---- merge (layer 2): out = relu(u + max(p0,p1)) fp32, streaming ----
__global__ __launch_bounds__(256) void merge_kernel(G g0, G g1, int N) {
    const G g = blockIdx.y ? g1 : g0;
    const int tot = N * (HID / 2);           // u32s per half array
    const unsigned int* __restrict__ p0 = (const unsigned int*)g.q;
    const unsigned int* __restrict__ p1 = p0 + (size_t)N * (HID / 2);
    for (int i = blockIdx.x * 256 + threadIdx.x; i < tot; i += gridDim.x * 256) {
        const unsigned int mm = pkmax(p0[i], p1[i]);
        const float2 uu = *(const float2*)(g.u + (size_t)i * 2);
        float2 o;                            // u + (-inf) -> fmax -> 0 (empty)
        o.x = fmaxf(uu.x + h2f(mm & 0xFFFFu), 0.f);
        o.y = fmaxf(uu.y + h2f(mm >> 16),     0.f);
        *(float2*)(g.out + (size_t)i * 2) = o;
    }
}

// ---------------- orchestration ----------------

extern "C" void kernel_launch(void* const* d_in, const int* in_sizes, int n_in,
                              void* d_out, int out_size, void* d_ws, size_t ws_size,
                              hipStream_t stream) {
    const float* x1  = (const float*)d_in[0];
    const int*   ei1 = (const int*)d_in[1];   // [2,E]: src row then dst row
    const float* x2  = (const float*)d_in[2];
    const int*   ei2 = (const int*)d_in[3];
    const float* W1  = (const float*)d_in[4];
    const float* b1  = (const float*)d_in[5];
    // d_in[6] = prelu_a: unused (identity on >=0)
    const float* W2  = (const float*)d_in[7];
    const float* b2  = (const float*)d_in[8];

    const int N   = in_sizes[0] / 32;
    const int E   = in_sizes[1] / 2;
    const int NBD = (N + TILE - 1) / TILE;    // 391 dst-buckets
    const int NB  = 2 * NBD;                  // 782 bin buckets (x src-half)
    float* out = (float*)d_out;

    const size_t rowB = (size_t)N * HID * sizeof(float);            // 12.8 MB
    const size_t vkB  = ((size_t)(N + 1) * HID * 2 + 63) & ~(size_t)63;
    const size_t qB   = ((size_t)2 * N * HID * 2 + 63) & ~(size_t)63; // 12.8 MB
    const size_t binB = ((size_t)NB * CAP * sizeof(int) + 63) & ~(size_t)63;
    const size_t nbB  = ((size_t)(NB + 2) * sizeof(int) + 63) & ~(size_t)63;
    const size_t wc1B = ((size_t)32 * 128 * 2 + 63) & ~(size_t)63;
    const size_t wc2B = ((size_t)64 * 128 * 2 + 63) & ~(size_t)63;

    const int bBlk = (E + 1024 * EPT - 1) / (1024 * EPT);   // 391 per graph
    const int gBlk = 512;
    const int pBlk = (32 * 64 + 64 * 64 + 2 * HID + 255) / 256;
    const int aggBlk2 = ((NBD + 1) / 2) * 8;  // XCD-partitioned 1D grid
    const int aggBlk1 = 2 * NBD;
    const int mBlk = 1024;

    _Float16* wc1 = nullptr;
    _Float16* wc2 = nullptr;

    auto run = [&](G ga, G gb, int ny) {
        // bcnt arrays contiguous across graphs: one memset when ny==2
        hipMemsetAsync(ga.bcnt, 0, (size_t)ny * nbB, stream);
        bin_kernel <<<dim3(bBlk, ny), 1024, 0, stream>>>(ga, gb, E, NB);
        gemm_mfma_kernel<32,0><<<dim3(gBlk, ny), 256, 0, stream>>>(ga, gb, wc1, b1, N);
        if (ny == 2) agg_kernel<1><<<aggBlk2, 256, 0, stream>>>(ga, gb, N, NBD, 1);
        else         agg_kernel<1><<<aggBlk1, 256, 0, stream>>>(ga, ga, N, NBD, 0);
        gemm_mfma_kernel<64,1><<<dim3(gBlk, ny), 256, 0, stream>>>(ga, gb, wc2, b2, N);
        if (ny == 2) agg_kernel<0><<<aggBlk2, 256, 0, stream>>>(ga, gb, N, NBD, 1);
        else         agg_kernel<0><<<aggBlk1, 256, 0, stream>>>(ga, ga, N, NBD, 0);
        merge_kernel<<<dim3(mBlk, ny), 256, 0, stream>>>(ga, gb, N);
    };

    char* ws = (char*)d_ws;
    const size_t needBoth =
        2 * rowB + 2 * binB + 2 * vkB + 2 * qB + wc1B + wc2B + 2 * nbB;

    if (ws_size >= needBoth) {
        float* u0 = (float*)ws;                  ws += rowB;
        float* u1 = (float*)ws;                  ws += rowB;
        unsigned int* bin0 = (unsigned int*)ws;  ws += binB;
        unsigned int* bin1 = (unsigned int*)ws;  ws += binB;
        unsigned short* vk0 = (unsigned short*)ws;  ws += vkB;
        unsigned short* vk1 = (unsigned short*)ws;  ws += vkB;
        unsigned short* q0 = (unsigned short*)ws;   ws += qB;
        unsigned short* q1 = (unsigned short*)ws;   ws += qB;
        wc1 = (_Float16*)ws;                     ws += wc1B;
        wc2 = (_Float16*)ws;                     ws += wc2B;
        int* bcnt0 = (int*)ws;                   ws += nbB;
        int* bcnt1 = (int*)ws;                   // contiguous with bcnt0

        G g0{x1, ei1, ei1 + E, bcnt0, bin0, u0, vk0, q0, out};
        G g1{x2, ei2, ei2 + E, bcnt1, bin1, u1, vk1, q1, out + (size_t)N * HID};
        prep_w_kernel<<<pBlk, 256, 0, stream>>>(W1, W2, wc1, wc2, vk0, vk1, N);
        run(g0, g1, 2);
    } else {
        // sequential fallback (~42 MB): one graph's buffers, reused
        float* u = (float*)ws;                   ws += rowB;
        unsigned int* bin = (unsigned int*)ws;   ws += binB;
        unsigned short* vk = (unsigned short*)ws;  ws += vkB;
        unsigned short* q = (unsigned short*)ws;   ws += qB;
        wc1 = (_Float16*)ws;                     ws += wc1B;
        wc2 = (_Float16*)ws;                     ws += wc2B;
        int* bcnt = (int*)ws;

        prep_w_kernel<<<pBlk, 256, 0, stream>>>(W1, W2, wc1, wc2, vk, vk, N);
        for (int g = 0; g < 2; ++g) {
            const int* ei = g ? ei2 : ei1;
            G gp{g ? x2 : x1, ei, ei + E, bcnt, bin,
                 u, vk, q, out + (size_t)g * N * HID};
            run(gp, gp, 1);
        }
    }
}

// Round 10
// 245.175 us; speedup vs baseline: 1.1469x; 1.1469x over previous
//
#include <hip/hip_runtime.h>
#include <hip/hip_fp16.h>

// SiameseEdgeConvNet: 2-layer EdgeConv (max aggr) on two graphs, shared weights.
// N=50000, E=1.6e6, dims 32 -> 64 -> 64.
//
// Algebra: msg = relu([xi, xj-xi] @ W + b) = relu(xi@A + xj@B + b),
//   A=W_lo-W_hi, B=W_hi.  u = x@A + b, v = x@B per node; ReLU monotone =>
//   out[d] = relu(u[d] + max_{e: dst=d} v[src_e]);  empty segment -> 0.
//   PReLU input >= 0 -> identity -> skipped.
//
// R22 = R20 (best, 252 us) + {agg 8-deep pad-x8, bin||gemm32 fusion}.
// Ledger (do NOT retry):
//   - R13 per-node global binning: 250 us (random 2B stores, 186 MB writes).
//   - R15 temporal half-row agg passes: FETCH 114->168 MB.
//   - R16 2 agg blocks/bucket (node halves): duplicate record scan, 55 us.
//   - R17 spatial CHANNEL-half x XCD: vk HBM 2x, FETCH 195 MB, 86 us.
//   - R18 bin short runs (1.3 rec): 68 us despite occ 2x. Bin tracks RUN
//     LENGTH: {1.3 rec -> 68} {2.6 -> 47.7} {5.2 -> <53} {10.5 -> <59}.
//   - R21 SRC-PARITY split: FETCH 114->62 MB (L2-residency worked) but agg
//     53->65 us. PROOF the gather floor is issue machinery (~9 cyc/record/CU
//     on divergent wave-loads), NOT memory level. Also halved list length ->
//     pad-to-x16 waste ~40%. Do not chase FETCH further.
// R22 changes:
//   * agg phase B back to 8-deep pipeline, lists padded to x8 (R14's proven
//     depth; 48 us best-ever agg). Mean-32 lists: pad waste 23% -> 12%.
//   * bin and gemm32 are data-independent (edges vs x) -> fused into ONE
//     dispatch with block-range roles (blocks [0,bBlk) bin at EPT=16/256t,
//     rest gemm32). Scatter latency slots absorb GEMM work; one less gap.

constexpr int HID   = 64;
constexpr int TILE  = 64;           // nodes per bucket (dst >> 6)
constexpr int TSH   = 6;            // log2(TILE)
constexpr int CAP   = 2560;         // records per bucket (mean 2048, +11s)
constexpr int MAXNB = 1024;         // max buckets (N <= 65536)
constexpr int EPT   = 16;           // edges per thread in bin path (256t)
constexpr int CAPN  = 96;           // per-node capacity (mean deg 32, max ~62)

typedef _Float16 half8 __attribute__((ext_vector_type(8)));
typedef float    f32x4 __attribute__((ext_vector_type(4)));

__device__ __forceinline__ unsigned int pkmax(unsigned int a, unsigned int b) {
    unsigned int d;
    asm("v_pk_max_f16 %0, %1, %2" : "=v"(d) : "v"(a), "v"(b));
    return d;
}
__device__ __forceinline__ unsigned short f2hbits(float f) {
    const __half h = __float2half_rn(f);
    return *reinterpret_cast<const unsigned short*>(&h);
}
__device__ __forceinline__ float h2f(unsigned int b16) {
    const unsigned short b = (unsigned short)b16;
    __half h;
    *reinterpret_cast<unsigned short*>(&h) = b;
    return __half2float(h);
}

struct G {                    // one graph's pointer set
    const float* x;           // [N,32] layer-1 input
    const int*   src;         // [E]
    const int*   dst;         // [E]
    int* bcnt;                // [NB]       bucket fill counters
    unsigned int* bin;        // [NB*CAP]   packed records (src<<6 | dst&63)
    float*          u;        // [N,64] fp32
    unsigned short* vk;       // [(N+1),64] fp16, permuted: uint2 slot m of a
                              //   row holds channels {m,m+16,m+32,m+48};
                              //   row N = -inf sentinel (set once in prep_w)
    _Float16*       h;        // [N,64] fp16 row-major — layer-1 output
    float*          out;      // [N,64] fp32 — final output
};

// ---- weight prep + vk sentinel row init ----
__global__ __launch_bounds__(256) void prep_w_kernel(
    const float* __restrict__ W1, const float* __restrict__ W2,
    _Float16* __restrict__ Wc1, _Float16* __restrict__ Wc2,
    unsigned short* __restrict__ vkS0, unsigned short* __restrict__ vkS1, int N)
{
    const int i = blockIdx.x * 256 + threadIdx.x;
    if (i < 32 * 64) {
        const int k = i >> 6, c = i & 63;
        const float lo = W1[k * 64 + c], hi = W1[(32 + k) * 64 + c];
        Wc1[k * 128 + c]      = (_Float16)(lo - hi);
        Wc1[k * 128 + 64 + c] = (_Float16)hi;
    }
    const int j = i - 32 * 64;
    if (j >= 0 && j < 64 * 64) {
        const int k = j >> 6, c = j & 63;
        const float lo = W2[k * 64 + c], hi = W2[(64 + k) * 64 + c];
        Wc2[k * 128 + c]      = (_Float16)(lo - hi);
        Wc2[k * 128 + 64 + c] = (_Float16)hi;
    }
    const int q = i - (32 * 64 + 64 * 64);
    if (q >= 0 && q < 2 * HID) {                 // sentinel rows = -inf fp16
        if (q < HID) vkS0[(size_t)N * HID + q]       = 0xFC00u;
        else         vkS1[(size_t)N * HID + (q-HID)] = 0xFC00u;
    }
}

// ---- fused: blocks [0,bBlk) = bin scatter; [bBlk, bBlk+gBlk) = gemm32 ----
// bin and gemm32 have no data dependency (edges vs x); co-residency lets the
// GEMM fill the scatter's latency slots.
__global__ __launch_bounds__(256) void bin_gemm32_kernel(
    G g0, G g1, int E, int NB, int N,
    const _Float16* __restrict__ Wc, const float* __restrict__ bias, int bBlk)
{
    const G g = blockIdx.y ? g1 : g0;

    if ((int)blockIdx.x < bBlk) {
        // ---------------- bin path (256t, EPT=16 -> 4096 edges/block) ------
        __shared__ int lh[MAXNB];   // local hist, then local write offset
        __shared__ int lb[MAXNB];   // reserved base per bucket
        for (int i = threadIdx.x; i < NB; i += 256) lh[i] = 0;
        __syncthreads();

        const int base = blockIdx.x * 256 * EPT;
        unsigned int rec[EPT];
        int bb[EPT];
        #pragma unroll
        for (int k = 0; k < EPT; ++k) {
            const int i = base + k * 256 + threadIdx.x;   // coalesced stream
            if (i < E) {
                const int d = g.dst[i];
                const int s = g.src[i];
                rec[k] = ((unsigned int)s << TSH) | (unsigned int)(d & (TILE - 1));
                bb[k]  = d >> TSH;
                atomicAdd(&lh[bb[k]], 1);
            } else bb[k] = -1;
        }
        __syncthreads();
        for (int t = threadIdx.x; t < NB; t += 256) {
            const int c = lh[t];
            lb[t] = c ? atomicAdd(&g.bcnt[t], c) : 0;   // range reservation
            lh[t] = 0;
        }
        __syncthreads();
        #pragma unroll
        for (int k = 0; k < EPT; ++k) {
            if (bb[k] >= 0) {
                const int off = atomicAdd(&lh[bb[k]], 1);
                const int pos = lb[bb[k]] + off;
                if (pos < CAP)                            // 11-sigma guard
                    g.bin[(size_t)bb[k] * CAP + pos] = rec[k];
            }
        }
        return;
    }

    // ---------------- gemm32 path: [u|v] = x @ Wc1; u += b1 ----------------
    constexpr int K = 32;
    const int lane = threadIdx.x & 63;
    const int m    = lane & 15;                // A row / D col-lane
    const int quad = lane >> 4;
    const int bx   = blockIdx.x - bBlk;
    const int wid  = (bx * 256 + threadIdx.x) >> 6;
    const int nW   = ((gridDim.x - bBlk) * 256) >> 6;

    half8 bf[8];                               // B[k=quad*8+j][n=16t+m]
    #pragma unroll
    for (int t = 0; t < 8; ++t)
        #pragma unroll
        for (int j = 0; j < 8; ++j)
            bf[t][j] = Wc[(quad * 8 + j) * 128 + t * 16 + m];

    float bv[4];
    #pragma unroll
    for (int t = 0; t < 4; ++t) bv[t] = bias[t * 16 + m];

    const int tiles = (N + 15) / 16;
    for (int tile = wid; tile < tiles; tile += nW) {
        const int nbase = tile * 16;
        const int nodeA = min(nbase + m, N - 1);
        const float4* rp = (const float4*)(g.x + (size_t)nodeA * K);

        half8 a;
        {
            const float4 f0 = rp[quad * 2];
            const float4 f1 = rp[quad * 2 + 1];
            a[0] = (_Float16)f0.x; a[1] = (_Float16)f0.y;
            a[2] = (_Float16)f0.z; a[3] = (_Float16)f0.w;
            a[4] = (_Float16)f1.x; a[5] = (_Float16)f1.y;
            a[6] = (_Float16)f1.z; a[7] = (_Float16)f1.w;
        }

        f32x4 acc[8];
        #pragma unroll
        for (int t = 0; t < 8; ++t) {
            acc[t] = (f32x4){0.f, 0.f, 0.f, 0.f};
            acc[t] = __builtin_amdgcn_mfma_f32_16x16x32_f16(
                a, bf[t], acc[t], 0, 0, 0);
        }

        #pragma unroll
        for (int r = 0; r < 4; ++r) {          // D[m=quad*4+r][n=lane&15]
            const int node = nbase + quad * 4 + r;
            if (node < N) {
                float* urow = g.u + (size_t)node * HID;
                #pragma unroll
                for (int t = 0; t < 4; ++t)
                    urow[t * 16 + m] = acc[t][r] + bv[t];
                const unsigned int e0 = f2hbits(acc[4][r]);   // channel m
                const unsigned int e1 = f2hbits(acc[5][r]);   // channel m+16
                const unsigned int e2 = f2hbits(acc[6][r]);   // channel m+32
                const unsigned int e3 = f2hbits(acc[7][r]);   // channel m+48
                uint2 pack;
                pack.x = (e1 << 16) | e0;
                pack.y = (e3 << 16) | e2;
                ((uint2*)(g.vk + (size_t)node * HID))[m] = pack;
            }
        }
    }
}

// ---- MFMA node GEMM layer 2: input = g.h fp16 row-major ----
__global__ __launch_bounds__(256) void gemm64_kernel(
    G g0, G g1, const _Float16* __restrict__ Wc,
    const float* __restrict__ bias, int N)
{
    const G g = blockIdx.y ? g1 : g0;
    constexpr int K = 64, KH = 2;
    const int lane = threadIdx.x & 63;
    const int m    = lane & 15;
    const int quad = lane >> 4;
    const int wid  = (blockIdx.x * 256 + threadIdx.x) >> 6;
    const int nW   = (gridDim.x * 256) >> 6;

    half8 bf[8][KH];
    #pragma unroll
    for (int t = 0; t < 8; ++t)
        #pragma unroll
        for (int hh = 0; hh < KH; ++hh)
            #pragma unroll
            for (int j = 0; j < 8; ++j)
                bf[t][hh][j] = Wc[(hh * 32 + quad * 8 + j) * 128 + t * 16 + m];

    float bv[4];
    #pragma unroll
    for (int t = 0; t < 4; ++t) bv[t] = bias[t * 16 + m];

    const int tiles = (N + 15) / 16;
    for (int tile = wid; tile < tiles; tile += nW) {
        const int nbase = tile * 16;
        const int nodeA = min(nbase + m, N - 1);
        const half8* rp = (const half8*)(g.h + (size_t)nodeA * K);

        half8 a[KH];
        #pragma unroll
        for (int hh = 0; hh < KH; ++hh) a[hh] = rp[hh * 4 + quad];

        f32x4 acc[8];
        #pragma unroll
        for (int t = 0; t < 8; ++t) {
            acc[t] = (f32x4){0.f, 0.f, 0.f, 0.f};
            #pragma unroll
            for (int hh = 0; hh < KH; ++hh)
                acc[t] = __builtin_amdgcn_mfma_f32_16x16x32_f16(
                    a[hh], bf[t][hh], acc[t], 0, 0, 0);
        }

        #pragma unroll
        for (int r = 0; r < 4; ++r) {          // D[m=quad*4+r][n=lane&15]
            const int node = nbase + quad * 4 + r;
            if (node < N) {
                float* urow = g.u + (size_t)node * HID;
                #pragma unroll
                for (int t = 0; t < 4; ++t)
                    urow[t * 16 + m] = acc[t][r] + bv[t];
                const unsigned int e0 = f2hbits(acc[4][r]);
                const unsigned int e1 = f2hbits(acc[5][r]);
                const unsigned int e2 = f2hbits(acc[6][r]);
                const unsigned int e3 = f2hbits(acc[7][r]);
                uint2 pack;
                pack.x = (e1 << 16) | e0;
                pack.y = (e3 << 16) | e2;
                ((uint2*)(g.vk + (size_t)node * HID))[m] = pack;
            }
        }
    }
}

// ---- aggregate: 256 threads per 64-node bucket, SINGLE scan ----
// Phase A: coalesced record read + LDS counting sort into per-node lists,
//   padded to multiples of 8 with sentinel src=N (-inf vk row).
// Phase B: 16 groups x 16 lanes, 4 sequential nodes/group; running max in
//   registers via v_pk_max_f16; full-row uint2 gathers, 8 in flight
//   (R14-proven depth; x8 padding halves sentinel waste vs x16).
// OUT16=true (layer 1): write h fp16 row-major.  false: write fp32 out.
template<bool OUT16>
__global__ __launch_bounds__(256) void agg_kernel(G g0, G g1, int N, int NB, int two) {
    int b, gi;
    if (two) {                       // XCD partition: bid%8 -> XCD (heuristic)
        const int bid = blockIdx.x;
        const int xcd = bid & 7;
        gi = xcd >> 2;               // XCD 0-3: graph 0, XCD 4-7: graph 1
        b  = (bid >> 3) * 4 + (xcd & 3);
    } else { gi = 0; b = blockIdx.x; }
    if (b >= NB) return;
    const G g = gi ? g1 : g0;

    __shared__ int lcnt[TILE];
    __shared__ alignas(16) unsigned short lrec[TILE][CAPN];  // 12.3 KB
    for (int i = threadIdx.x; i < TILE; i += 256) lcnt[i] = 0;
    __syncthreads();

    const int cnt = min(g.bcnt[b], CAP);
    const unsigned int* __restrict__ bp = g.bin + (size_t)b * CAP;
    for (int i = threadIdx.x; i < cnt; i += 256) {
        const unsigned int rec = bp[i];
        const int d = rec & (TILE - 1);
        const int p = atomicAdd(&lcnt[d], 1);
        if (p < CAPN) lrec[d][p] = (unsigned short)(rec >> TSH);
    }
    __syncthreads();
    for (int t = threadIdx.x; t < TILE; t += 256) {   // pad to x8 w/ sentinel
        const int c  = min(lcnt[t], CAPN);
        const int cp = (c + 7) & ~7;
        for (int p = c; p < cp; ++p) lrec[t][p] = (unsigned short)N;
        lcnt[t] = cp;
    }
    __syncthreads();

    const int grp = threadIdx.x >> 4;        // 16 groups of 16 lanes
    const int sub = threadIdx.x & 15;
    const uint2* __restrict__ vk2 = (const uint2*)g.vk;

    #pragma unroll
    for (int i = 0; i < 4; ++i) {
        const int nl = grp + 16 * i;
        const int n  = b * TILE + nl;
        if (n >= N) continue;
        const int cp = lcnt[nl];

        unsigned int m0 = 0xFC00FC00u, m1 = 0xFC00FC00u;   // -inf halves
        for (int j = 0; j < cp; j += 8) {
            const uint4 rq = *(const uint4*)(&lrec[nl][j]);  // 8 recs, bcast
            unsigned int s[8];
            s[0] = rq.x & 0xFFFFu; s[1] = rq.x >> 16;
            s[2] = rq.y & 0xFFFFu; s[3] = rq.y >> 16;
            s[4] = rq.z & 0xFFFFu; s[5] = rq.z >> 16;
            s[6] = rq.w & 0xFFFFu; s[7] = rq.w >> 16;
            uint2 a[8];
            #pragma unroll
            for (int k = 0; k < 8; ++k) a[k] = vk2[(size_t)s[k] * 16 + sub];
            #pragma unroll
            for (int k = 0; k < 8; ++k) {
                m0 = pkmax(m0, a[k].x);
                m1 = pkmax(m1, a[k].y);
            }
        }

        const bool has = cp > 0;
        const float* __restrict__ urow = g.u + (size_t)n * HID;
        const float r0 = has ? fmaxf(urow[sub]      + h2f(m0 & 0xFFFFu), 0.f) : 0.f;
        const float r1 = has ? fmaxf(urow[sub + 16] + h2f(m0 >> 16),     0.f) : 0.f;
        const float r2 = has ? fmaxf(urow[sub + 32] + h2f(m1 & 0xFFFFu), 0.f) : 0.f;
        const float r3 = has ? fmaxf(urow[sub + 48] + h2f(m1 >> 16),     0.f) : 0.f;
        if constexpr (OUT16) {       // fp16 h, same rounding gemm64 would do
            _Float16* hrow = g.h + (size_t)n * HID;
            hrow[sub]      = (_Float16)r0;
            hrow[sub + 16] = (_Float16)r1;
            hrow[sub + 32] = (_Float16)r2;
            hrow[sub + 48] = (_Float16)r3;
        } else {
            float* __restrict__ orow = g.out + (size_t)n * HID;
            orow[sub]      = r0;
            orow[sub + 16] = r1;
            orow[sub + 32] = r2;
            orow[sub + 48] = r3;
        }
    }
}

// ---------------- orchestration ----------------

extern "C" void kernel_launch(void* const* d_in, const int* in_sizes, int n_in,
                              void* d_out, int out_size, void* d_ws, size_t ws_size,
                              hipStream_t stream) {
    const float* x1  = (const float*)d_in[0];
    const int*   ei1 = (const int*)d_in[1];   // [2,E]: src row then dst row
    const float* x2  = (const float*)d_in[2];
    const int*   ei2 = (const int*)d_in[3];
    const float* W1  = (const float*)d_in[4];
    const float* b1  = (const float*)d_in[5];
    // d_in[6] = prelu_a: unused (identity on >=0)
    const float* W2  = (const float*)d_in[7];
    const float* b2  = (const float*)d_in[8];

    const int N  = in_sizes[0] / 32;
    const int E  = in_sizes[1] / 2;
    const int NB = (N + TILE - 1) / TILE;     // 782 for N=50000
    float* out = (float*)d_out;

    const size_t rowB = (size_t)N * HID * sizeof(float);            // 12.8 MB
    const size_t vkB  = ((size_t)(N + 1) * HID * 2 + 63) & ~(size_t)63;
    const size_t hB   = ((size_t)N * HID * 2 + 63) & ~(size_t)63;   //  6.4 MB
    const size_t binB = ((size_t)NB * CAP * sizeof(int) + 63) & ~(size_t)63;
    const size_t nbB  = ((size_t)(NB + 2) * sizeof(int) + 63) & ~(size_t)63;
    const size_t wc1B = ((size_t)32 * 128 * 2 + 63) & ~(size_t)63;
    const size_t wc2B = ((size_t)64 * 128 * 2 + 63) & ~(size_t)63;

    const int bBlk = (E + 256 * EPT - 1) / (256 * EPT);   // 391 per graph
    const int gBlk = 512;
    const int pBlk = (32 * 64 + 64 * 64 + 2 * HID + 255) / 256;
    const int aggBlk2 = ((NB + 3) / 4) * 8;   // XCD-partitioned 1D grid
    const int aggBlk1 = NB;

    _Float16* wc1 = nullptr;
    _Float16* wc2 = nullptr;

    auto run = [&](G ga, G gb, int ny) {
        // bcnt arrays contiguous across graphs: one memset when ny==2
        hipMemsetAsync(ga.bcnt, 0, (size_t)ny * nbB, stream);
        bin_gemm32_kernel<<<dim3(bBlk + gBlk, ny), 256, 0, stream>>>(
            ga, gb, E, NB, N, wc1, b1, bBlk);
        if (ny == 2) agg_kernel<true><<<aggBlk2, 256, 0, stream>>>(ga, gb, N, NB, 1);
        else         agg_kernel<true><<<aggBlk1, 256, 0, stream>>>(ga, ga, N, NB, 0);
        gemm64_kernel<<<dim3(gBlk, ny), 256, 0, stream>>>(ga, gb, wc2, b2, N);
        if (ny == 2) agg_kernel<false><<<aggBlk2, 256, 0, stream>>>(ga, gb, N, NB, 1);
        else         agg_kernel<false><<<aggBlk1, 256, 0, stream>>>(ga, ga, N, NB, 0);
    };

    char* ws = (char*)d_ws;
    const size_t needBoth =
        2 * rowB + 2 * binB + 2 * vkB + 2 * hB + wc1B + wc2B + 2 * nbB;

    if (ws_size >= needBoth) {
        float* u0 = (float*)ws;                  ws += rowB;
        float* u1 = (float*)ws;                  ws += rowB;
        unsigned int* bin0 = (unsigned int*)ws;  ws += binB;
        unsigned int* bin1 = (unsigned int*)ws;  ws += binB;
        unsigned short* vk0 = (unsigned short*)ws;  ws += vkB;
        unsigned short* vk1 = (unsigned short*)ws;  ws += vkB;
        _Float16* h0 = (_Float16*)ws;            ws += hB;
        _Float16* h1 = (_Float16*)ws;            ws += hB;
        wc1 = (_Float16*)ws;                     ws += wc1B;
        wc2 = (_Float16*)ws;                     ws += wc2B;
        int* bcnt0 = (int*)ws;                   ws += nbB;
        int* bcnt1 = (int*)ws;                   // contiguous with bcnt0

        G g0{x1, ei1, ei1 + E, bcnt0, bin0, u0, vk0, h0, out};
        G g1{x2, ei2, ei2 + E, bcnt1, bin1, u1, vk1, h1, out + (size_t)N * HID};
        prep_w_kernel<<<pBlk, 256, 0, stream>>>(W1, W2, wc1, wc2, vk0, vk1, N);
        run(g0, g1, 2);
    } else {
        // sequential fallback (~34 MB): one graph's buffers, reused
        float* u = (float*)ws;                   ws += rowB;
        unsigned int* bin = (unsigned int*)ws;   ws += binB;
        unsigned short* vk = (unsigned short*)ws;  ws += vkB;
        _Float16* h = (_Float16*)ws;             ws += hB;
        wc1 = (_Float16*)ws;                     ws += wc1B;
        wc2 = (_Float16*)ws;                     ws += wc2B;
        int* bcnt = (int*)ws;

        prep_w_kernel<<<pBlk, 256, 0, stream>>>(W1, W2, wc1, wc2, vk, vk, N);
        for (int g = 0; g < 2; ++g) {
            const int* ei = g ? ei2 : ei1;
            G gp{g ? x2 : x1, ei, ei + E, bcnt, bin,
                 u, vk, h, out + (size_t)g * N * HID};
            run(gp, gp, 1);
        }
    }
}

// Round 11
// 228.687 us; speedup vs baseline: 1.2296x; 1.0721x over previous
//
#include <hip/hip_runtime.h>
#include <hip/hip_fp16.h>

// SiameseEdgeConvNet: 2-layer EdgeConv (max aggr) on two graphs, shared weights.
// N=50000, E=1.6e6, dims 32 -> 64 -> 64.
//
// Algebra: msg = relu([xi, xj-xi] @ W + b) = relu(xi@A + xj@B + b),
//   A=W_lo-W_hi, B=W_hi.  u = x@A + b, v = x@B per node; ReLU monotone =>
//   out[d] = relu(u[d] + max_{e: dst=d} v[src_e]);  empty segment -> 0.
//   PReLU input >= 0 -> identity -> skipped.
//
// R23 = R22 (best, 245 us) + agg phase-B gathers widened to uint4/8-lane.
// Ledger (do NOT retry):
//   - R13 per-node global binning: 250 us (random 2B stores, 186 MB writes).
//   - R15 temporal half-row agg passes: FETCH 114->168 MB.
//   - R16 2 agg blocks/bucket (node halves): duplicate record scan, 55 us.
//   - R17 spatial CHANNEL-half x XCD: vk HBM 2x, FETCH 195 MB, 86 us.
//   - R18 bin short runs (1.3 rec): 68 us despite occ 2x. Bin tracks RUN
//     LENGTH: {1.3 rec -> 68} {2.6 -> 47.7} {5.2 -> <53} {10.5 -> <59}.
//   - R21 SRC-PARITY split: FETCH 114->62 MB (L2-residency worked) but agg
//     53->65 us. PROOF: gather floor is issue machinery, not memory level.
// R23 experiment (pre-committed read): one wave-gather currently delivers 4
//   rows (16-lane x uint2). TA address-walk is per-lane-quad, so widening to
//   8-lane x uint4 delivers 8 rows per instruction at the same address-walk
//   cost -> halves gather instrs/record. If agg drops to ~40 us: cost was
//   per-instruction. If unchanged: cost is per-cache-line -> floor reached,
//   declare roofline.

constexpr int HID   = 64;
constexpr int TILE  = 64;           // nodes per bucket (dst >> 6)
constexpr int TSH   = 6;            // log2(TILE)
constexpr int CAP   = 2560;         // records per bucket (mean 2048, +11s)
constexpr int MAXNB = 1024;         // max buckets (N <= 65536)
constexpr int EPT   = 16;           // edges per thread in bin path (256t)
constexpr int CAPN  = 96;           // per-node capacity (mean deg 32, max ~62)

typedef _Float16 half8 __attribute__((ext_vector_type(8)));
typedef float    f32x4 __attribute__((ext_vector_type(4)));

__device__ __forceinline__ unsigned int pkmax(unsigned int a, unsigned int b) {
    unsigned int d;
    asm("v_pk_max_f16 %0, %1, %2" : "=v"(d) : "v"(a), "v"(b));
    return d;
}
__device__ __forceinline__ unsigned short f2hbits(float f) {
    const __half h = __float2half_rn(f);
    return *reinterpret_cast<const unsigned short*>(&h);
}
__device__ __forceinline__ float h2f(unsigned int b16) {
    const unsigned short b = (unsigned short)b16;
    __half h;
    *reinterpret_cast<unsigned short*>(&h) = b;
    return __half2float(h);
}

struct G {                    // one graph's pointer set
    const float* x;           // [N,32] layer-1 input
    const int*   src;         // [E]
    const int*   dst;         // [E]
    int* bcnt;                // [NB]       bucket fill counters
    unsigned int* bin;        // [NB*CAP]   packed records (src<<6 | dst&63)
    float*          u;        // [N,64] fp32
    unsigned short* vk;       // [(N+1),64] fp16, permuted: uint slot q of a
                              //   row: q=2m -> ch {m,m+16}, q=2m+1 ->
                              //   ch {m+32,m+48}; row N = -inf sentinel
    _Float16*       h;        // [N,64] fp16 row-major — layer-1 output
    float*          out;      // [N,64] fp32 — final output
};

// ---- weight prep + vk sentinel row init ----
__global__ __launch_bounds__(256) void prep_w_kernel(
    const float* __restrict__ W1, const float* __restrict__ W2,
    _Float16* __restrict__ Wc1, _Float16* __restrict__ Wc2,
    unsigned short* __restrict__ vkS0, unsigned short* __restrict__ vkS1, int N)
{
    const int i = blockIdx.x * 256 + threadIdx.x;
    if (i < 32 * 64) {
        const int k = i >> 6, c = i & 63;
        const float lo = W1[k * 64 + c], hi = W1[(32 + k) * 64 + c];
        Wc1[k * 128 + c]      = (_Float16)(lo - hi);
        Wc1[k * 128 + 64 + c] = (_Float16)hi;
    }
    const int j = i - 32 * 64;
    if (j >= 0 && j < 64 * 64) {
        const int k = j >> 6, c = j & 63;
        const float lo = W2[k * 64 + c], hi = W2[(64 + k) * 64 + c];
        Wc2[k * 128 + c]      = (_Float16)(lo - hi);
        Wc2[k * 128 + 64 + c] = (_Float16)hi;
    }
    const int q = i - (32 * 64 + 64 * 64);
    if (q >= 0 && q < 2 * HID) {                 // sentinel rows = -inf fp16
        if (q < HID) vkS0[(size_t)N * HID + q]       = 0xFC00u;
        else         vkS1[(size_t)N * HID + (q-HID)] = 0xFC00u;
    }
}

// ---- fused: blocks [0,bBlk) = bin scatter; [bBlk, bBlk+gBlk) = gemm32 ----
__global__ __launch_bounds__(256) void bin_gemm32_kernel(
    G g0, G g1, int E, int NB, int N,
    const _Float16* __restrict__ Wc, const float* __restrict__ bias, int bBlk)
{
    const G g = blockIdx.y ? g1 : g0;

    if ((int)blockIdx.x < bBlk) {
        // ---------------- bin path (256t, EPT=16 -> 4096 edges/block) ------
        __shared__ int lh[MAXNB];   // local hist, then local write offset
        __shared__ int lb[MAXNB];   // reserved base per bucket
        for (int i = threadIdx.x; i < NB; i += 256) lh[i] = 0;
        __syncthreads();

        const int base = blockIdx.x * 256 * EPT;
        unsigned int rec[EPT];
        int bb[EPT];
        #pragma unroll
        for (int k = 0; k < EPT; ++k) {
            const int i = base + k * 256 + threadIdx.x;   // coalesced stream
            if (i < E) {
                const int d = g.dst[i];
                const int s = g.src[i];
                rec[k] = ((unsigned int)s << TSH) | (unsigned int)(d & (TILE - 1));
                bb[k]  = d >> TSH;
                atomicAdd(&lh[bb[k]], 1);
            } else bb[k] = -1;
        }
        __syncthreads();
        for (int t = threadIdx.x; t < NB; t += 256) {
            const int c = lh[t];
            lb[t] = c ? atomicAdd(&g.bcnt[t], c) : 0;   // range reservation
            lh[t] = 0;
        }
        __syncthreads();
        #pragma unroll
        for (int k = 0; k < EPT; ++k) {
            if (bb[k] >= 0) {
                const int off = atomicAdd(&lh[bb[k]], 1);
                const int pos = lb[bb[k]] + off;
                if (pos < CAP)                            // 11-sigma guard
                    g.bin[(size_t)bb[k] * CAP + pos] = rec[k];
            }
        }
        return;
    }

    // ---------------- gemm32 path: [u|v] = x @ Wc1; u += b1 ----------------
    constexpr int K = 32;
    const int lane = threadIdx.x & 63;
    const int m    = lane & 15;                // A row / D col-lane
    const int quad = lane >> 4;
    const int bx   = blockIdx.x - bBlk;
    const int wid  = (bx * 256 + threadIdx.x) >> 6;
    const int nW   = ((gridDim.x - bBlk) * 256) >> 6;

    half8 bf[8];                               // B[k=quad*8+j][n=16t+m]
    #pragma unroll
    for (int t = 0; t < 8; ++t)
        #pragma unroll
        for (int j = 0; j < 8; ++j)
            bf[t][j] = Wc[(quad * 8 + j) * 128 + t * 16 + m];

    float bv[4];
    #pragma unroll
    for (int t = 0; t < 4; ++t) bv[t] = bias[t * 16 + m];

    const int tiles = (N + 15) / 16;
    for (int tile = wid; tile < tiles; tile += nW) {
        const int nbase = tile * 16;
        const int nodeA = min(nbase + m, N - 1);
        const float4* rp = (const float4*)(g.x + (size_t)nodeA * K);

        half8 a;
        {
            const float4 f0 = rp[quad * 2];
            const float4 f1 = rp[quad * 2 + 1];
            a[0] = (_Float16)f0.x; a[1] = (_Float16)f0.y;
            a[2] = (_Float16)f0.z; a[3] = (_Float16)f0.w;
            a[4] = (_Float16)f1.x; a[5] = (_Float16)f1.y;
            a[6] = (_Float16)f1.z; a[7] = (_Float16)f1.w;
        }

        f32x4 acc[8];
        #pragma unroll
        for (int t = 0; t < 8; ++t) {
            acc[t] = (f32x4){0.f, 0.f, 0.f, 0.f};
            acc[t] = __builtin_amdgcn_mfma_f32_16x16x32_f16(
                a, bf[t], acc[t], 0, 0, 0);
        }

        #pragma unroll
        for (int r = 0; r < 4; ++r) {          // D[m=quad*4+r][n=lane&15]
            const int node = nbase + quad * 4 + r;
            if (node < N) {
                float* urow = g.u + (size_t)node * HID;
                #pragma unroll
                for (int t = 0; t < 4; ++t)
                    urow[t * 16 + m] = acc[t][r] + bv[t];
                const unsigned int e0 = f2hbits(acc[4][r]);   // channel m
                const unsigned int e1 = f2hbits(acc[5][r]);   // channel m+16
                const unsigned int e2 = f2hbits(acc[6][r]);   // channel m+32
                const unsigned int e3 = f2hbits(acc[7][r]);   // channel m+48
                uint2 pack;
                pack.x = (e1 << 16) | e0;
                pack.y = (e3 << 16) | e2;
                ((uint2*)(g.vk + (size_t)node * HID))[m] = pack;
            }
        }
    }
}

// ---- MFMA node GEMM layer 2: input = g.h fp16 row-major ----
__global__ __launch_bounds__(256) void gemm64_kernel(
    G g0, G g1, const _Float16* __restrict__ Wc,
    const float* __restrict__ bias, int N)
{
    const G g = blockIdx.y ? g1 : g0;
    constexpr int K = 64, KH = 2;
    const int lane = threadIdx.x & 63;
    const int m    = lane & 15;
    const int quad = lane >> 4;
    const int wid  = (blockIdx.x * 256 + threadIdx.x) >> 6;
    const int nW   = (gridDim.x * 256) >> 6;

    half8 bf[8][KH];
    #pragma unroll
    for (int t = 0; t < 8; ++t)
        #pragma unroll
        for (int hh = 0; hh < KH; ++hh)
            #pragma unroll
            for (int j = 0; j < 8; ++j)
                bf[t][hh][j] = Wc[(hh * 32 + quad * 8 + j) * 128 + t * 16 + m];

    float bv[4];
    #pragma unroll
    for (int t = 0; t < 4; ++t) bv[t] = bias[t * 16 + m];

    const int tiles = (N + 15) / 16;
    for (int tile = wid; tile < tiles; tile += nW) {
        const int nbase = tile * 16;
        const int nodeA = min(nbase + m, N - 1);
        const half8* rp = (const half8*)(g.h + (size_t)nodeA * K);

        half8 a[KH];
        #pragma unroll
        for (int hh = 0; hh < KH; ++hh) a[hh] = rp[hh * 4 + quad];

        f32x4 acc[8];
        #pragma unroll
        for (int t = 0; t < 8; ++t) {
            acc[t] = (f32x4){0.f, 0.f, 0.f, 0.f};
            #pragma unroll
            for (int hh = 0; hh < KH; ++hh)
                acc[t] = __builtin_amdgcn_mfma_f32_16x16x32_f16(
                    a[hh], bf[t][hh], acc[t], 0, 0, 0);
        }

        #pragma unroll
        for (int r = 0; r < 4; ++r) {          // D[m=quad*4+r][n=lane&15]
            const int node = nbase + quad * 4 + r;
            if (node < N) {
                float* urow = g.u + (size_t)node * HID;
                #pragma unroll
                for (int t = 0; t < 4; ++t)
                    urow[t * 16 + m] = acc[t][r] + bv[t];
                const unsigned int e0 = f2hbits(acc[4][r]);
                const unsigned int e1 = f2hbits(acc[5][r]);
                const unsigned int e2 = f2hbits(acc[6][r]);
                const unsigned int e3 = f2hbits(acc[7][r]);
                uint2 pack;
                pack.x = (e1 << 16) | e0;
                pack.y = (e3 << 16) | e2;
                ((uint2*)(g.vk + (size_t)node * HID))[m] = pack;
            }
        }
    }
}

// ---- aggregate: 256 threads per 64-node bucket, SINGLE scan ----
// Phase A: coalesced record read + LDS counting sort into per-node lists,
//   padded to multiples of 8 with sentinel src=N (-inf vk row).
// Phase B: 32 groups x 8 lanes, 2 sequential nodes/group; full-row uint4
//   gathers (8 rows per wave-instruction, 2x R22's payload/instr), 8 in
//   flight, v_pk_max_f16 accumulate into 4 regs (8 channels/lane).
// OUT16=true (layer 1): write h fp16 row-major.  false: write fp32 out.
template<bool OUT16>
__global__ __launch_bounds__(256) void agg_kernel(G g0, G g1, int N, int NB, int two) {
    int b, gi;
    if (two) {                       // XCD partition: bid%8 -> XCD (heuristic)
        const int bid = blockIdx.x;
        const int xcd = bid & 7;
        gi = xcd >> 2;               // XCD 0-3: graph 0, XCD 4-7: graph 1
        b  = (bid >> 3) * 4 + (xcd & 3);
    } else { gi = 0; b = blockIdx.x; }
    if (b >= NB) return;
    const G g = gi ? g1 : g0;

    __shared__ int lcnt[TILE];
    __shared__ alignas(16) unsigned short lrec[TILE][CAPN];  // 12.3 KB
    for (int i = threadIdx.x; i < TILE; i += 256) lcnt[i] = 0;
    __syncthreads();

    const int cnt = min(g.bcnt[b], CAP);
    const unsigned int* __restrict__ bp = g.bin + (size_t)b * CAP;
    for (int i = threadIdx.x; i < cnt; i += 256) {
        const unsigned int rec = bp[i];
        const int d = rec & (TILE - 1);
        const int p = atomicAdd(&lcnt[d], 1);
        if (p < CAPN) lrec[d][p] = (unsigned short)(rec >> TSH);
    }
    __syncthreads();
    for (int t = threadIdx.x; t < TILE; t += 256) {   // pad to x8 w/ sentinel
        const int c  = min(lcnt[t], CAPN);
        const int cp = (c + 7) & ~7;
        for (int p = c; p < cp; ++p) lrec[t][p] = (unsigned short)N;
        lcnt[t] = cp;
    }
    __syncthreads();

    const int grp = threadIdx.x >> 3;        // 32 groups of 8 lanes
    const int sub = threadIdx.x & 7;
    const uint4* __restrict__ vk4 = (const uint4*)g.vk;   // 8 uint4 per row

    #pragma unroll
    for (int i = 0; i < 2; ++i) {
        const int nl = grp + 32 * i;
        const int n  = b * TILE + nl;
        if (n >= N) continue;
        const int cp = lcnt[nl];

        // lane sub covers uint slots 4sub..4sub+3:
        //   m0: ch {2sub, 2sub+16}   m1: ch {2sub+32, 2sub+48}
        //   m2: ch {2sub+1, 2sub+17} m3: ch {2sub+33, 2sub+49}
        unsigned int m0 = 0xFC00FC00u, m1 = m0, m2 = m0, m3 = m0;
        for (int j = 0; j < cp; j += 8) {
            const uint4 rq = *(const uint4*)(&lrec[nl][j]);  // 8 recs, bcast
            unsigned int s[8];
            s[0] = rq.x & 0xFFFFu; s[1] = rq.x >> 16;
            s[2] = rq.y & 0xFFFFu; s[3] = rq.y >> 16;
            s[4] = rq.z & 0xFFFFu; s[5] = rq.z >> 16;
            s[6] = rq.w & 0xFFFFu; s[7] = rq.w >> 16;
            uint4 a[8];
            #pragma unroll
            for (int k = 0; k < 8; ++k) a[k] = vk4[(size_t)s[k] * 8 + sub];
            #pragma unroll
            for (int k = 0; k < 8; ++k) {
                m0 = pkmax(m0, a[k].x);
                m1 = pkmax(m1, a[k].y);
                m2 = pkmax(m2, a[k].z);
                m3 = pkmax(m3, a[k].w);
            }
        }

        const bool has = cp > 0;
        const float2* __restrict__ u2 =
            (const float2*)(g.u + (size_t)n * HID);      // pair {2sub,2sub+1}
        const float2 ua = u2[sub], ub = u2[sub + 8],
                     uc = u2[sub + 16], ud = u2[sub + 24];
        float r0, r1, r2, r3, r4, r5, r6, r7;
        r0 = has ? fmaxf(ua.x + h2f(m0 & 0xFFFFu), 0.f) : 0.f;  // ch 2sub
        r1 = has ? fmaxf(ua.y + h2f(m2 & 0xFFFFu), 0.f) : 0.f;  // ch 2sub+1
        r2 = has ? fmaxf(ub.x + h2f(m0 >> 16),     0.f) : 0.f;  // +16
        r3 = has ? fmaxf(ub.y + h2f(m2 >> 16),     0.f) : 0.f;
        r4 = has ? fmaxf(uc.x + h2f(m1 & 0xFFFFu), 0.f) : 0.f;  // +32
        r5 = has ? fmaxf(uc.y + h2f(m3 & 0xFFFFu), 0.f) : 0.f;
        r6 = has ? fmaxf(ud.x + h2f(m1 >> 16),     0.f) : 0.f;  // +48
        r7 = has ? fmaxf(ud.y + h2f(m3 >> 16),     0.f) : 0.f;
        if constexpr (OUT16) {       // fp16 h, same rounding gemm64 would do
            unsigned int* hrow = (unsigned int*)(g.h + (size_t)n * HID);
            hrow[sub]      = (unsigned int)f2hbits(r0) | ((unsigned int)f2hbits(r1) << 16);
            hrow[sub + 8]  = (unsigned int)f2hbits(r2) | ((unsigned int)f2hbits(r3) << 16);
            hrow[sub + 16] = (unsigned int)f2hbits(r4) | ((unsigned int)f2hbits(r5) << 16);
            hrow[sub + 24] = (unsigned int)f2hbits(r6) | ((unsigned int)f2hbits(r7) << 16);
        } else {
            float2* orow = (float2*)(g.out + (size_t)n * HID);
            orow[sub]      = (float2){r0, r1};
            orow[sub + 8]  = (float2){r2, r3};
            orow[sub + 16] = (float2){r4, r5};
            orow[sub + 24] = (float2){r6, r7};
        }
    }
}

// ---------------- orchestration ----------------

extern "C" void kernel_launch(void* const* d_in, const int* in_sizes, int n_in,
                              void* d_out, int out_size, void* d_ws, size_t ws_size,
                              hipStream_t stream) {
    const float* x1  = (const float*)d_in[0];
    const int*   ei1 = (const int*)d_in[1];   // [2,E]: src row then dst row
    const float* x2  = (const float*)d_in[2];
    const int*   ei2 = (const int*)d_in[3];
    const float* W1  = (const float*)d_in[4];
    const float* b1  = (const float*)d_in[5];
    // d_in[6] = prelu_a: unused (identity on >=0)
    const float* W2  = (const float*)d_in[7];
    const float* b2  = (const float*)d_in[8];

    const int N  = in_sizes[0] / 32;
    const int E  = in_sizes[1] / 2;
    const int NB = (N + TILE - 1) / TILE;     // 782 for N=50000
    float* out = (float*)d_out;

    const size_t rowB = (size_t)N * HID * sizeof(float);            // 12.8 MB
    const size_t vkB  = ((size_t)(N + 1) * HID * 2 + 63) & ~(size_t)63;
    const size_t hB   = ((size_t)N * HID * 2 + 63) & ~(size_t)63;   //  6.4 MB
    const size_t binB = ((size_t)NB * CAP * sizeof(int) + 63) & ~(size_t)63;
    const size_t nbB  = ((size_t)(NB + 2) * sizeof(int) + 63) & ~(size_t)63;
    const size_t wc1B = ((size_t)32 * 128 * 2 + 63) & ~(size_t)63;
    const size_t wc2B = ((size_t)64 * 128 * 2 + 63) & ~(size_t)63;

    const int bBlk = (E + 256 * EPT - 1) / (256 * EPT);   // 391 per graph
    const int gBlk = 512;
    const int pBlk = (32 * 64 + 64 * 64 + 2 * HID + 255) / 256;
    const int aggBlk2 = ((NB + 3) / 4) * 8;   // XCD-partitioned 1D grid
    const int aggBlk1 = NB;

    _Float16* wc1 = nullptr;
    _Float16* wc2 = nullptr;

    auto run = [&](G ga, G gb, int ny) {
        // bcnt arrays contiguous across graphs: one memset when ny==2
        hipMemsetAsync(ga.bcnt, 0, (size_t)ny * nbB, stream);
        bin_gemm32_kernel<<<dim3(bBlk + gBlk, ny), 256, 0, stream>>>(
            ga, gb, E, NB, N, wc1, b1, bBlk);
        if (ny == 2) agg_kernel<true><<<aggBlk2, 256, 0, stream>>>(ga, gb, N, NB, 1);
        else         agg_kernel<true><<<aggBlk1, 256, 0, stream>>>(ga, ga, N, NB, 0);
        gemm64_kernel<<<dim3(gBlk, ny), 256, 0, stream>>>(ga, gb, wc2, b2, N);
        if (ny == 2) agg_kernel<false><<<aggBlk2, 256, 0, stream>>>(ga, gb, N, NB, 1);
        else         agg_kernel<false><<<aggBlk1, 256, 0, stream>>>(ga, ga, N, NB, 0);
    };

    char* ws = (char*)d_ws;
    const size_t needBoth =
        2 * rowB + 2 * binB + 2 * vkB + 2 * hB + wc1B + wc2B + 2 * nbB;

    if (ws_size >= needBoth) {
        float* u0 = (float*)ws;                  ws += rowB;
        float* u1 = (float*)ws;                  ws += rowB;
        unsigned int* bin0 = (unsigned int*)ws;  ws += binB;
        unsigned int* bin1 = (unsigned int*)ws;  ws += binB;
        unsigned short* vk0 = (unsigned short*)ws;  ws += vkB;
        unsigned short* vk1 = (unsigned short*)ws;  ws += vkB;
        _Float16* h0 = (_Float16*)ws;            ws += hB;
        _Float16* h1 = (_Float16*)ws;            ws += hB;
        wc1 = (_Float16*)ws;                     ws += wc1B;
        wc2 = (_Float16*)ws;                     ws += wc2B;
        int* bcnt0 = (int*)ws;                   ws += nbB;
        int* bcnt1 = (int*)ws;                   // contiguous with bcnt0

        G g0{x1, ei1, ei1 + E, bcnt0, bin0, u0, vk0, h0, out};
        G g1{x2, ei2, ei2 + E, bcnt1, bin1, u1, vk1, h1, out + (size_t)N * HID};
        prep_w_kernel<<<pBlk, 256, 0, stream>>>(W1, W2, wc1, wc2, vk0, vk1, N);
        run(g0, g1, 2);
    } else {
        // sequential fallback (~34 MB): one graph's buffers, reused
        float* u = (float*)ws;                   ws += rowB;
        unsigned int* bin = (unsigned int*)ws;   ws += binB;
        unsigned short* vk = (unsigned short*)ws;  ws += vkB;
        _Float16* h = (_Float16*)ws;             ws += hB;
        wc1 = (_Float16*)ws;                     ws += wc1B;
        wc2 = (_Float16*)ws;                     ws += wc2B;
        int* bcnt = (int*)ws;

        prep_w_kernel<<<pBlk, 256, 0, stream>>>(W1, W2, wc1, wc2, vk, vk, N);
        for (int g = 0; g < 2; ++g) {
            const int* ei = g ? ei2 : ei1;
            G gp{g ? x2 : x1, ei, ei + E, bcnt, bin,
                 u, vk, h, out + (size_t)g * N * HID};
            run(gp, gp, 1);
        }
    }
}

// Round 12
// 224.980 us; speedup vs baseline: 1.2499x; 1.0165x over previous
//
#include <hip/hip_runtime.h>
#include <hip/hip_fp16.h>

// SiameseEdgeConvNet: 2-layer EdgeConv (max aggr) on two graphs, shared weights.
// N=50000, E=1.6e6, dims 32 -> 64 -> 64.
//
// Algebra: msg = relu([xi, xj-xi] @ W + b) = relu(xi@A + xj@B + b),
//   A=W_lo-W_hi, B=W_hi.  u = x@A + b, v = x@B per node; ReLU monotone =>
//   out[d] = relu(u[d] + max_{e: dst=d} v[src_e]);  empty segment -> 0.
//   PReLU input >= 0 -> identity -> skipped.
//
// R24 = R23 (best, 228.7 us) + LDS-staged sorted scatter in the bin path.
// Ledger (do NOT retry):
//   - R13 per-node global binning: 250 us (random 2B stores, 186 MB writes).
//   - R15 temporal half-row agg passes: FETCH 114->168 MB.
//   - R16 2 agg blocks/bucket (node halves): duplicate record scan, 55 us.
//   - R17 spatial CHANNEL-half x XCD: vk HBM 2x, FETCH 195 MB, 86 us.
//   - R18 bin short runs (1.3 rec): 68 us despite occ 2x.
//   - R21 SRC-PARITY split: FETCH 114->62 MB but agg 53->65 us. PROOF the
//     gather floor is issue machinery, not memory level.
//   - R23 CONFIRMED per-instruction floor: uint2->uint4 gathers (4->8
//     rows/instr) dropped agg 51 -> <45 us.
// R24 experiment (pre-committed read): bin's scatter wave-stores present 64
//   scattered bucket addresses -> worst-case TA walk, the same per-
//   instruction cost R23 fixed in agg. Stage in LDS: hist -> block prefix
//   scan -> place sorted (LDS atomics) -> stream out, so consecutive lanes
//   write consecutive addresses within each ~5.2-record run (~12-24 segments
//   per wave-store instead of 64). If bin_gemm32 drops to ~35 us: issue-
//   bound confirmed. If unchanged (WRITE ~76 MB too): RFO/line-bound ->
//   structural floor, declare roofline.

constexpr int HID   = 64;
constexpr int TILE  = 64;           // nodes per bucket (dst >> 6)
constexpr int TSH   = 6;            // log2(TILE)
constexpr int CAP   = 2560;         // records per bucket (mean 2048, +11s)
constexpr int MAXNB = 1024;         // max buckets (N <= 65536)
constexpr int EPT   = 16;           // edges per thread in bin path (256t)
constexpr int CAPN  = 96;           // per-node capacity (mean deg 32, max ~62)

typedef _Float16 half8 __attribute__((ext_vector_type(8)));
typedef float    f32x4 __attribute__((ext_vector_type(4)));

__device__ __forceinline__ unsigned int pkmax(unsigned int a, unsigned int b) {
    unsigned int d;
    asm("v_pk_max_f16 %0, %1, %2" : "=v"(d) : "v"(a), "v"(b));
    return d;
}
__device__ __forceinline__ unsigned short f2hbits(float f) {
    const __half h = __float2half_rn(f);
    return *reinterpret_cast<const unsigned short*>(&h);
}
__device__ __forceinline__ float h2f(unsigned int b16) {
    const unsigned short b = (unsigned short)b16;
    __half h;
    *reinterpret_cast<unsigned short*>(&h) = b;
    return __half2float(h);
}

struct G {                    // one graph's pointer set
    const float* x;           // [N,32] layer-1 input
    const int*   src;         // [E]
    const int*   dst;         // [E]
    int* bcnt;                // [NB]       bucket fill counters
    unsigned int* bin;        // [NB*CAP]   packed records (src<<6 | dst&63)
    float*          u;        // [N,64] fp32
    unsigned short* vk;       // [(N+1),64] fp16, permuted: uint slot q of a
                              //   row: q=2m -> ch {m,m+16}, q=2m+1 ->
                              //   ch {m+32,m+48}; row N = -inf sentinel
    _Float16*       h;        // [N,64] fp16 row-major — layer-1 output
    float*          out;      // [N,64] fp32 — final output
};

// ---- weight prep + vk sentinel row init ----
__global__ __launch_bounds__(256) void prep_w_kernel(
    const float* __restrict__ W1, const float* __restrict__ W2,
    _Float16* __restrict__ Wc1, _Float16* __restrict__ Wc2,
    unsigned short* __restrict__ vkS0, unsigned short* __restrict__ vkS1, int N)
{
    const int i = blockIdx.x * 256 + threadIdx.x;
    if (i < 32 * 64) {
        const int k = i >> 6, c = i & 63;
        const float lo = W1[k * 64 + c], hi = W1[(32 + k) * 64 + c];
        Wc1[k * 128 + c]      = (_Float16)(lo - hi);
        Wc1[k * 128 + 64 + c] = (_Float16)hi;
    }
    const int j = i - 32 * 64;
    if (j >= 0 && j < 64 * 64) {
        const int k = j >> 6, c = j & 63;
        const float lo = W2[k * 64 + c], hi = W2[(64 + k) * 64 + c];
        Wc2[k * 128 + c]      = (_Float16)(lo - hi);
        Wc2[k * 128 + 64 + c] = (_Float16)hi;
    }
    const int q = i - (32 * 64 + 64 * 64);
    if (q >= 0 && q < 2 * HID) {                 // sentinel rows = -inf fp16
        if (q < HID) vkS0[(size_t)N * HID + q]       = 0xFC00u;
        else         vkS1[(size_t)N * HID + (q-HID)] = 0xFC00u;
    }
}

// ---- fused: blocks [0,bBlk) = bin (LDS-staged sorted scatter); rest gemm32
__global__ __launch_bounds__(256) void bin_gemm32_kernel(
    G g0, G g1, int E, int NB, int N,
    const _Float16* __restrict__ Wc, const float* __restrict__ bias, int bBlk)
{
    const G g = blockIdx.y ? g1 : g0;

    if ((int)blockIdx.x < bBlk) {
        // -------- bin path (256t, EPT=16 -> 4096 edges/block) --------------
        __shared__ int lh[MAXNB];                 // hist, then place cursor
        __shared__ int lof[MAXNB];                // local exclusive prefix
        __shared__ int gbase[MAXNB];              // t*CAP + reserve - lof[t]
        __shared__ unsigned int   srec[256 * EPT];   // 16 KB sorted records
        __shared__ unsigned short sbkt[256 * EPT];   //  8 KB bucket ids
        __shared__ int wsum[4];

        const int tid = threadIdx.x;
        for (int i = tid; i < NB; i += 256) lh[i] = 0;
        __syncthreads();

        const int base = blockIdx.x * 256 * EPT;
        unsigned int rec[EPT];
        int bb[EPT];
        #pragma unroll
        for (int k = 0; k < EPT; ++k) {
            const int i = base + k * 256 + tid;   // coalesced stream
            if (i < E) {
                const int d = g.dst[i];
                const int s = g.src[i];
                rec[k] = ((unsigned int)s << TSH) | (unsigned int)(d & (TILE - 1));
                bb[k]  = d >> TSH;
                atomicAdd(&lh[bb[k]], 1);
            } else bb[k] = -1;
        }
        __syncthreads();

        // block exclusive prefix over lh[0..NB): 4 buckets/thread + wave scan
        constexpr int CH = MAXNB / 256;           // 4
        const int c0 = tid * CH;
        int cl[CH], s = 0;
        #pragma unroll
        for (int c = 0; c < CH; ++c) {
            cl[c] = (c0 + c < NB) ? lh[c0 + c] : 0;
            s += cl[c];
        }
        const int lane = tid & 63, wv = tid >> 6;
        int v = s;
        #pragma unroll
        for (int d = 1; d < 64; d <<= 1) {
            const int t = __shfl_up(v, d);
            if (lane >= d) v += t;
        }
        if (lane == 63) wsum[wv] = v;
        __syncthreads();
        int run = v - s;                          // wave-exclusive
        for (int w = 0; w < wv; ++w) run += wsum[w];
        #pragma unroll
        for (int c = 0; c < CH; ++c) {
            if (c0 + c < NB) lof[c0 + c] = run;
            run += cl[c];
        }
        __syncthreads();

        // global range reservation + flattened base; reset cursor
        for (int t = tid; t < NB; t += 256) {
            const int cc = lh[t];
            const int rb = cc ? atomicAdd(&g.bcnt[t], cc) : 0;
            gbase[t] = t * CAP + rb - lof[t];
            lh[t] = 0;
        }
        __syncthreads();

        // place records sorted-by-bucket into LDS
        #pragma unroll
        for (int k = 0; k < EPT; ++k) {
            if (bb[k] >= 0) {
                const int p = lof[bb[k]] + atomicAdd(&lh[bb[k]], 1);
                srec[p] = rec[k];
                sbkt[p] = (unsigned short)bb[k];
            }
        }
        __syncthreads();

        // stream out: consecutive lanes -> consecutive addresses per run
        const int total = min(256 * EPT, E - base);
        for (int i = tid; i < total; i += 256) {
            const int bkt  = sbkt[i];
            const int gidx = gbase[bkt] + i;
            if (gidx < (bkt + 1) * CAP)           // 11-sigma overflow guard
                g.bin[gidx] = srec[i];
        }
        return;
    }

    // ---------------- gemm32 path: [u|v] = x @ Wc1; u += b1 ----------------
    constexpr int K = 32;
    const int lane = threadIdx.x & 63;
    const int m    = lane & 15;                // A row / D col-lane
    const int quad = lane >> 4;
    const int bx   = blockIdx.x - bBlk;
    const int wid  = (bx * 256 + threadIdx.x) >> 6;
    const int nW   = ((gridDim.x - bBlk) * 256) >> 6;

    half8 bf[8];                               // B[k=quad*8+j][n=16t+m]
    #pragma unroll
    for (int t = 0; t < 8; ++t)
        #pragma unroll
        for (int j = 0; j < 8; ++j)
            bf[t][j] = Wc[(quad * 8 + j) * 128 + t * 16 + m];

    float bv[4];
    #pragma unroll
    for (int t = 0; t < 4; ++t) bv[t] = bias[t * 16 + m];

    const int tiles = (N + 15) / 16;
    for (int tile = wid; tile < tiles; tile += nW) {
        const int nbase = tile * 16;
        const int nodeA = min(nbase + m, N - 1);
        const float4* rp = (const float4*)(g.x + (size_t)nodeA * K);

        half8 a;
        {
            const float4 f0 = rp[quad * 2];
            const float4 f1 = rp[quad * 2 + 1];
            a[0] = (_Float16)f0.x; a[1] = (_Float16)f0.y;
            a[2] = (_Float16)f0.z; a[3] = (_Float16)f0.w;
            a[4] = (_Float16)f1.x; a[5] = (_Float16)f1.y;
            a[6] = (_Float16)f1.z; a[7] = (_Float16)f1.w;
        }

        f32x4 acc[8];
        #pragma unroll
        for (int t = 0; t < 8; ++t) {
            acc[t] = (f32x4){0.f, 0.f, 0.f, 0.f};
            acc[t] = __builtin_amdgcn_mfma_f32_16x16x32_f16(
                a, bf[t], acc[t], 0, 0, 0);
        }

        #pragma unroll
        for (int r = 0; r < 4; ++r) {          // D[m=quad*4+r][n=lane&15]
            const int node = nbase + quad * 4 + r;
            if (node < N) {
                float* urow = g.u + (size_t)node * HID;
                #pragma unroll
                for (int t = 0; t < 4; ++t)
                    urow[t * 16 + m] = acc[t][r] + bv[t];
                const unsigned int e0 = f2hbits(acc[4][r]);   // channel m
                const unsigned int e1 = f2hbits(acc[5][r]);   // channel m+16
                const unsigned int e2 = f2hbits(acc[6][r]);   // channel m+32
                const unsigned int e3 = f2hbits(acc[7][r]);   // channel m+48
                uint2 pack;
                pack.x = (e1 << 16) | e0;
                pack.y = (e3 << 16) | e2;
                ((uint2*)(g.vk + (size_t)node * HID))[m] = pack;
            }
        }
    }
}

// ---- MFMA node GEMM layer 2: input = g.h fp16 row-major ----
__global__ __launch_bounds__(256) void gemm64_kernel(
    G g0, G g1, const _Float16* __restrict__ Wc,
    const float* __restrict__ bias, int N)
{
    const G g = blockIdx.y ? g1 : g0;
    constexpr int K = 64, KH = 2;
    const int lane = threadIdx.x & 63;
    const int m    = lane & 15;
    const int quad = lane >> 4;
    const int wid  = (blockIdx.x * 256 + threadIdx.x) >> 6;
    const int nW   = (gridDim.x * 256) >> 6;

    half8 bf[8][KH];
    #pragma unroll
    for (int t = 0; t < 8; ++t)
        #pragma unroll
        for (int hh = 0; hh < KH; ++hh)
            #pragma unroll
            for (int j = 0; j < 8; ++j)
                bf[t][hh][j] = Wc[(hh * 32 + quad * 8 + j) * 128 + t * 16 + m];

    float bv[4];
    #pragma unroll
    for (int t = 0; t < 4; ++t) bv[t] = bias[t * 16 + m];

    const int tiles = (N + 15) / 16;
    for (int tile = wid; tile < tiles; tile += nW) {
        const int nbase = tile * 16;
        const int nodeA = min(nbase + m, N - 1);
        const half8* rp = (const half8*)(g.h + (size_t)nodeA * K);

        half8 a[KH];
        #pragma unroll
        for (int hh = 0; hh < KH; ++hh) a[hh] = rp[hh * 4 + quad];

        f32x4 acc[8];
        #pragma unroll
        for (int t = 0; t < 8; ++t) {
            acc[t] = (f32x4){0.f, 0.f, 0.f, 0.f};
            #pragma unroll
            for (int hh = 0; hh < KH; ++hh)
                acc[t] = __builtin_amdgcn_mfma_f32_16x16x32_f16(
                    a[hh], bf[t][hh], acc[t], 0, 0, 0);
        }

        #pragma unroll
        for (int r = 0; r < 4; ++r) {          // D[m=quad*4+r][n=lane&15]
            const int node = nbase + quad * 4 + r;
            if (node < N) {
                float* urow = g.u + (size_t)node * HID;
                #pragma unroll
                for (int t = 0; t < 4; ++t)
                    urow[t * 16 + m] = acc[t][r] + bv[t];
                const unsigned int e0 = f2hbits(acc[4][r]);
                const unsigned int e1 = f2hbits(acc[5][r]);
                const unsigned int e2 = f2hbits(acc[6][r]);
                const unsigned int e3 = f2hbits(acc[7][r]);
                uint2 pack;
                pack.x = (e1 << 16) | e0;
                pack.y = (e3 << 16) | e2;
                ((uint2*)(g.vk + (size_t)node * HID))[m] = pack;
            }
        }
    }
}

// ---- aggregate: 256 threads per 64-node bucket, SINGLE scan ----
// Phase A: coalesced record read + LDS counting sort into per-node lists,
//   padded to multiples of 8 with sentinel src=N (-inf vk row).
// Phase B: 32 groups x 8 lanes, 2 sequential nodes/group; full-row uint4
//   gathers (8 rows per wave-instruction), 8 in flight, v_pk_max_f16.
// OUT16=true (layer 1): write h fp16 row-major.  false: write fp32 out.
template<bool OUT16>
__global__ __launch_bounds__(256) void agg_kernel(G g0, G g1, int N, int NB, int two) {
    int b, gi;
    if (two) {                       // XCD partition: bid%8 -> XCD (heuristic)
        const int bid = blockIdx.x;
        const int xcd = bid & 7;
        gi = xcd >> 2;               // XCD 0-3: graph 0, XCD 4-7: graph 1
        b  = (bid >> 3) * 4 + (xcd & 3);
    } else { gi = 0; b = blockIdx.x; }
    if (b >= NB) return;
    const G g = gi ? g1 : g0;

    __shared__ int lcnt[TILE];
    __shared__ alignas(16) unsigned short lrec[TILE][CAPN];  // 12.3 KB
    for (int i = threadIdx.x; i < TILE; i += 256) lcnt[i] = 0;
    __syncthreads();

    const int cnt = min(g.bcnt[b], CAP);
    const unsigned int* __restrict__ bp = g.bin + (size_t)b * CAP;
    for (int i = threadIdx.x; i < cnt; i += 256) {
        const unsigned int rec = bp[i];
        const int d = rec & (TILE - 1);
        const int p = atomicAdd(&lcnt[d], 1);
        if (p < CAPN) lrec[d][p] = (unsigned short)(rec >> TSH);
    }
    __syncthreads();
    for (int t = threadIdx.x; t < TILE; t += 256) {   // pad to x8 w/ sentinel
        const int c  = min(lcnt[t], CAPN);
        const int cp = (c + 7) & ~7;
        for (int p = c; p < cp; ++p) lrec[t][p] = (unsigned short)N;
        lcnt[t] = cp;
    }
    __syncthreads();

    const int grp = threadIdx.x >> 3;        // 32 groups of 8 lanes
    const int sub = threadIdx.x & 7;
    const uint4* __restrict__ vk4 = (const uint4*)g.vk;   // 8 uint4 per row

    #pragma unroll
    for (int i = 0; i < 2; ++i) {
        const int nl = grp + 32 * i;
        const int n  = b * TILE + nl;
        if (n >= N) continue;
        const int cp = lcnt[nl];

        // lane sub covers uint slots 4sub..4sub+3:
        //   m0: ch {2sub, 2sub+16}   m1: ch {2sub+32, 2sub+48}
        //   m2: ch {2sub+1, 2sub+17} m3: ch {2sub+33, 2sub+49}
        unsigned int m0 = 0xFC00FC00u, m1 = m0, m2 = m0, m3 = m0;
        for (int j = 0; j < cp; j += 8) {
            const uint4 rq = *(const uint4*)(&lrec[nl][j]);  // 8 recs, bcast
            unsigned int s[8];
            s[0] = rq.x & 0xFFFFu; s[1] = rq.x >> 16;
            s[2] = rq.y & 0xFFFFu; s[3] = rq.y >> 16;
            s[4] = rq.z & 0xFFFFu; s[5] = rq.z >> 16;
            s[6] = rq.w & 0xFFFFu; s[7] = rq.w >> 16;
            uint4 a[8];
            #pragma unroll
            for (int k = 0; k < 8; ++k) a[k] = vk4[(size_t)s[k] * 8 + sub];
            #pragma unroll
            for (int k = 0; k < 8; ++k) {
                m0 = pkmax(m0, a[k].x);
                m1 = pkmax(m1, a[k].y);
                m2 = pkmax(m2, a[k].z);
                m3 = pkmax(m3, a[k].w);
            }
        }

        const bool has = cp > 0;
        const float2* __restrict__ u2 =
            (const float2*)(g.u + (size_t)n * HID);      // pair {2sub,2sub+1}
        const float2 ua = u2[sub], ub = u2[sub + 8],
                     uc = u2[sub + 16], ud = u2[sub + 24];
        float r0, r1, r2, r3, r4, r5, r6, r7;
        r0 = has ? fmaxf(ua.x + h2f(m0 & 0xFFFFu), 0.f) : 0.f;  // ch 2sub
        r1 = has ? fmaxf(ua.y + h2f(m2 & 0xFFFFu), 0.f) : 0.f;  // ch 2sub+1
        r2 = has ? fmaxf(ub.x + h2f(m0 >> 16),     0.f) : 0.f;  // +16
        r3 = has ? fmaxf(ub.y + h2f(m2 >> 16),     0.f) : 0.f;
        r4 = has ? fmaxf(uc.x + h2f(m1 & 0xFFFFu), 0.f) : 0.f;  // +32
        r5 = has ? fmaxf(uc.y + h2f(m3 & 0xFFFFu), 0.f) : 0.f;
        r6 = has ? fmaxf(ud.x + h2f(m1 >> 16),     0.f) : 0.f;  // +48
        r7 = has ? fmaxf(ud.y + h2f(m3 >> 16),     0.f) : 0.f;
        if constexpr (OUT16) {       // fp16 h, same rounding gemm64 would do
            unsigned int* hrow = (unsigned int*)(g.h + (size_t)n * HID);
            hrow[sub]      = (unsigned int)f2hbits(r0) | ((unsigned int)f2hbits(r1) << 16);
            hrow[sub + 8]  = (unsigned int)f2hbits(r2) | ((unsigned int)f2hbits(r3) << 16);
            hrow[sub + 16] = (unsigned int)f2hbits(r4) | ((unsigned int)f2hbits(r5) << 16);
            hrow[sub + 24] = (unsigned int)f2hbits(r6) | ((unsigned int)f2hbits(r7) << 16);
        } else {
            float2* orow = (float2*)(g.out + (size_t)n * HID);
            orow[sub]      = (float2){r0, r1};
            orow[sub + 8]  = (float2){r2, r3};
            orow[sub + 16] = (float2){r4, r5};
            orow[sub + 24] = (float2){r6, r7};
        }
    }
}

// ---------------- orchestration ----------------

extern "C" void kernel_launch(void* const* d_in, const int* in_sizes, int n_in,
                              void* d_out, int out_size, void* d_ws, size_t ws_size,
                              hipStream_t stream) {
    const float* x1  = (const float*)d_in[0];
    const int*   ei1 = (const int*)d_in[1];   // [2,E]: src row then dst row
    const float* x2  = (const float*)d_in[2];
    const int*   ei2 = (const int*)d_in[3];
    const float* W1  = (const float*)d_in[4];
    const float* b1  = (const float*)d_in[5];
    // d_in[6] = prelu_a: unused (identity on >=0)
    const float* W2  = (const float*)d_in[7];
    const float* b2  = (const float*)d_in[8];

    const int N  = in_sizes[0] / 32;
    const int E  = in_sizes[1] / 2;
    const int NB = (N + TILE - 1) / TILE;     // 782 for N=50000
    float* out = (float*)d_out;

    const size_t rowB = (size_t)N * HID * sizeof(float);            // 12.8 MB
    const size_t vkB  = ((size_t)(N + 1) * HID * 2 + 63) & ~(size_t)63;
    const size_t hB   = ((size_t)N * HID * 2 + 63) & ~(size_t)63;   //  6.4 MB
    const size_t binB = ((size_t)NB * CAP * sizeof(int) + 63) & ~(size_t)63;
    const size_t nbB  = ((size_t)(NB + 2) * sizeof(int) + 63) & ~(size_t)63;
    const size_t wc1B = ((size_t)32 * 128 * 2 + 63) & ~(size_t)63;
    const size_t wc2B = ((size_t)64 * 128 * 2 + 63) & ~(size_t)63;

    const int bBlk = (E + 256 * EPT - 1) / (256 * EPT);   // 391 per graph
    const int gBlk = 512;
    const int pBlk = (32 * 64 + 64 * 64 + 2 * HID + 255) / 256;
    const int aggBlk2 = ((NB + 3) / 4) * 8;   // XCD-partitioned 1D grid
    const int aggBlk1 = NB;

    _Float16* wc1 = nullptr;
    _Float16* wc2 = nullptr;

    auto run = [&](G ga, G gb, int ny) {
        // bcnt arrays contiguous across graphs: one memset when ny==2
        hipMemsetAsync(ga.bcnt, 0, (size_t)ny * nbB, stream);
        bin_gemm32_kernel<<<dim3(bBlk + gBlk, ny), 256, 0, stream>>>(
            ga, gb, E, NB, N, wc1, b1, bBlk);
        if (ny == 2) agg_kernel<true><<<aggBlk2, 256, 0, stream>>>(ga, gb, N, NB, 1);
        else         agg_kernel<true><<<aggBlk1, 256, 0, stream>>>(ga, ga, N, NB, 0);
        gemm64_kernel<<<dim3(gBlk, ny), 256, 0, stream>>>(ga, gb, wc2, b2, N);
        if (ny == 2) agg_kernel<false><<<aggBlk2, 256, 0, stream>>>(ga, gb, N, NB, 1);
        else         agg_kernel<false><<<aggBlk1, 256, 0, stream>>>(ga, ga, N, NB, 0);
    };

    char* ws = (char*)d_ws;
    const size_t needBoth =
        2 * rowB + 2 * binB + 2 * vkB + 2 * hB + wc1B + wc2B + 2 * nbB;

    if (ws_size >= needBoth) {
        float* u0 = (float*)ws;                  ws += rowB;
        float* u1 = (float*)ws;                  ws += rowB;
        unsigned int* bin0 = (unsigned int*)ws;  ws += binB;
        unsigned int* bin1 = (unsigned int*)ws;  ws += binB;
        unsigned short* vk0 = (unsigned short*)ws;  ws += vkB;
        unsigned short* vk1 = (unsigned short*)ws;  ws += vkB;
        _Float16* h0 = (_Float16*)ws;            ws += hB;
        _Float16* h1 = (_Float16*)ws;            ws += hB;
        wc1 = (_Float16*)ws;                     ws += wc1B;
        wc2 = (_Float16*)ws;                     ws += wc2B;
        int* bcnt0 = (int*)ws;                   ws += nbB;
        int* bcnt1 = (int*)ws;                   // contiguous with bcnt0

        G g0{x1, ei1, ei1 + E, bcnt0, bin0, u0, vk0, h0, out};
        G g1{x2, ei2, ei2 + E, bcnt1, bin1, u1, vk1, h1, out + (size_t)N * HID};
        prep_w_kernel<<<pBlk, 256, 0, stream>>>(W1, W2, wc1, wc2, vk0, vk1, N);
        run(g0, g1, 2);
    } else {
        // sequential fallback (~34 MB): one graph's buffers, reused
        float* u = (float*)ws;                   ws += rowB;
        unsigned int* bin = (unsigned int*)ws;   ws += binB;
        unsigned short* vk = (unsigned short*)ws;  ws += vkB;
        _Float16* h = (_Float16*)ws;             ws += hB;
        wc1 = (_Float16*)ws;                     ws += wc1B;
        wc2 = (_Float16*)ws;                     ws += wc2B;
        int* bcnt = (int*)ws;

        prep_w_kernel<<<pBlk, 256, 0, stream>>>(W1, W2, wc1, wc2, vk, vk, N);
        for (int g = 0; g < 2; ++g) {
            const int* ei = g ? ei2 : ei1;
            G gp{g ? x2 : x1, ei, ei + E, bcnt, bin,
                 u, vk, h, out + (size_t)g * N * HID};
            run(gp, gp, 1);
        }
    }
}

// Round 13
// 224.481 us; speedup vs baseline: 1.2527x; 1.0022x over previous
//
#include <hip/hip_runtime.h>
#include <hip/hip_fp16.h>

// SiameseEdgeConvNet: 2-layer EdgeConv (max aggr) on two graphs, shared weights.
// N=50000, E=1.6e6, dims 32 -> 64 -> 64.
//
// Algebra: msg = relu([xi, xj-xi] @ W + b) = relu(xi@A + xj@B + b),
//   A=W_lo-W_hi, B=W_hi.  u = x@A + b, v = x@B per node; ReLU monotone =>
//   out[d] = relu(u[d] + max_{e: dst=d} v[src_e]);  empty segment -> 0.
//   PReLU input >= 0 -> identity -> skipped.
//
// R25 = R24 (best, 225.0 us) + 2-stage software pipeline in agg phase B.
// Ledger (do NOT retry):
//   - R13 per-node global binning: 250 us (random 2B stores, 186 MB writes).
//   - R15 temporal half-row agg passes: FETCH 114->168 MB.
//   - R16 2 agg blocks/bucket (node halves): duplicate record scan, 55 us.
//   - R17 spatial CHANNEL-half x XCD: vk HBM 2x, FETCH 195 MB, 86 us.
//   - R18 bin short runs (1.3 rec): 68 us despite occ 2x.
//   - R21 SRC-PARITY split: FETCH 114->62 MB but agg 53->65 us. PROOF the
//     gather floor is issue machinery, not memory level.
//   - R23 CONFIRMED per-instruction cost: uint2->uint4 gathers (4->8
//     rows/instr) dropped agg 51 -> 44 us. Max load width reached.
//   - R24 CONFIRMED for scatter too: LDS-staged sorted scatter dropped
//     bin_gemm32 45.5 -> <44 us (out of top-5).
// R25 experiment (pre-committed read): agg's j-loop is a runtime loop ->
//   compiler waits vmcnt before pkmax and cannot issue next chunk's gathers
//   across the backedge: ~5 serial {issue 8, stall ~350cyc, consume} rounds
//   per node. Ping-pong buffers issue chunk c+1 BEFORE consuming chunk c ->
//   16 gathers in flight, stall overlapped with pkmax. If agg -> ~34 us:
//   latency-chain confirmed. If unchanged: per-CU TA issue saturated ->
//   structural floor (VALU/HBM/LDS/occupancy all ruled out R19-R25).

constexpr int HID   = 64;
constexpr int TILE  = 64;           // nodes per bucket (dst >> 6)
constexpr int TSH   = 6;            // log2(TILE)
constexpr int CAP   = 2560;         // records per bucket (mean 2048, +11s)
constexpr int MAXNB = 1024;         // max buckets (N <= 65536)
constexpr int EPT   = 16;           // edges per thread in bin path (256t)
constexpr int CAPN  = 96;           // per-node capacity (mean deg 32, max ~62)

typedef _Float16 half8 __attribute__((ext_vector_type(8)));
typedef float    f32x4 __attribute__((ext_vector_type(4)));

__device__ __forceinline__ unsigned int pkmax(unsigned int a, unsigned int b) {
    unsigned int d;
    asm("v_pk_max_f16 %0, %1, %2" : "=v"(d) : "v"(a), "v"(b));
    return d;
}
__device__ __forceinline__ unsigned short f2hbits(float f) {
    const __half h = __float2half_rn(f);
    return *reinterpret_cast<const unsigned short*>(&h);
}
__device__ __forceinline__ float h2f(unsigned int b16) {
    const unsigned short b = (unsigned short)b16;
    __half h;
    *reinterpret_cast<unsigned short*>(&h) = b;
    return __half2float(h);
}

struct G {                    // one graph's pointer set
    const float* x;           // [N,32] layer-1 input
    const int*   src;         // [E]
    const int*   dst;         // [E]
    int* bcnt;                // [NB]       bucket fill counters
    unsigned int* bin;        // [NB*CAP]   packed records (src<<6 | dst&63)
    float*          u;        // [N,64] fp32
    unsigned short* vk;       // [(N+1),64] fp16, permuted: uint slot q of a
                              //   row: q=2m -> ch {m,m+16}, q=2m+1 ->
                              //   ch {m+32,m+48}; row N = -inf sentinel
    _Float16*       h;        // [N,64] fp16 row-major — layer-1 output
    float*          out;      // [N,64] fp32 — final output
};

// ---- weight prep + vk sentinel row init ----
__global__ __launch_bounds__(256) void prep_w_kernel(
    const float* __restrict__ W1, const float* __restrict__ W2,
    _Float16* __restrict__ Wc1, _Float16* __restrict__ Wc2,
    unsigned short* __restrict__ vkS0, unsigned short* __restrict__ vkS1, int N)
{
    const int i = blockIdx.x * 256 + threadIdx.x;
    if (i < 32 * 64) {
        const int k = i >> 6, c = i & 63;
        const float lo = W1[k * 64 + c], hi = W1[(32 + k) * 64 + c];
        Wc1[k * 128 + c]      = (_Float16)(lo - hi);
        Wc1[k * 128 + 64 + c] = (_Float16)hi;
    }
    const int j = i - 32 * 64;
    if (j >= 0 && j < 64 * 64) {
        const int k = j >> 6, c = j & 63;
        const float lo = W2[k * 64 + c], hi = W2[(64 + k) * 64 + c];
        Wc2[k * 128 + c]      = (_Float16)(lo - hi);
        Wc2[k * 128 + 64 + c] = (_Float16)hi;
    }
    const int q = i - (32 * 64 + 64 * 64);
    if (q >= 0 && q < 2 * HID) {                 // sentinel rows = -inf fp16
        if (q < HID) vkS0[(size_t)N * HID + q]       = 0xFC00u;
        else         vkS1[(size_t)N * HID + (q-HID)] = 0xFC00u;
    }
}

// ---- fused: blocks [0,bBlk) = bin (LDS-staged sorted scatter); rest gemm32
__global__ __launch_bounds__(256) void bin_gemm32_kernel(
    G g0, G g1, int E, int NB, int N,
    const _Float16* __restrict__ Wc, const float* __restrict__ bias, int bBlk)
{
    const G g = blockIdx.y ? g1 : g0;

    if ((int)blockIdx.x < bBlk) {
        // -------- bin path (256t, EPT=16 -> 4096 edges/block) --------------
        __shared__ int lh[MAXNB];                 // hist, then place cursor
        __shared__ int lof[MAXNB];                // local exclusive prefix
        __shared__ int gbase[MAXNB];              // t*CAP + reserve - lof[t]
        __shared__ unsigned int   srec[256 * EPT];   // 16 KB sorted records
        __shared__ unsigned short sbkt[256 * EPT];   //  8 KB bucket ids
        __shared__ int wsum[4];

        const int tid = threadIdx.x;
        for (int i = tid; i < NB; i += 256) lh[i] = 0;
        __syncthreads();

        const int base = blockIdx.x * 256 * EPT;
        unsigned int rec[EPT];
        int bb[EPT];
        #pragma unroll
        for (int k = 0; k < EPT; ++k) {
            const int i = base + k * 256 + tid;   // coalesced stream
            if (i < E) {
                const int d = g.dst[i];
                const int s = g.src[i];
                rec[k] = ((unsigned int)s << TSH) | (unsigned int)(d & (TILE - 1));
                bb[k]  = d >> TSH;
                atomicAdd(&lh[bb[k]], 1);
            } else bb[k] = -1;
        }
        __syncthreads();

        // block exclusive prefix over lh[0..NB): 4 buckets/thread + wave scan
        constexpr int CH = MAXNB / 256;           // 4
        const int c0 = tid * CH;
        int cl[CH], s = 0;
        #pragma unroll
        for (int c = 0; c < CH; ++c) {
            cl[c] = (c0 + c < NB) ? lh[c0 + c] : 0;
            s += cl[c];
        }
        const int lane = tid & 63, wv = tid >> 6;
        int v = s;
        #pragma unroll
        for (int d = 1; d < 64; d <<= 1) {
            const int t = __shfl_up(v, d);
            if (lane >= d) v += t;
        }
        if (lane == 63) wsum[wv] = v;
        __syncthreads();
        int run = v - s;                          // wave-exclusive
        for (int w = 0; w < wv; ++w) run += wsum[w];
        #pragma unroll
        for (int c = 0; c < CH; ++c) {
            if (c0 + c < NB) lof[c0 + c] = run;
            run += cl[c];
        }
        __syncthreads();

        // global range reservation + flattened base; reset cursor
        for (int t = tid; t < NB; t += 256) {
            const int cc = lh[t];
            const int rb = cc ? atomicAdd(&g.bcnt[t], cc) : 0;
            gbase[t] = t * CAP + rb - lof[t];
            lh[t] = 0;
        }
        __syncthreads();

        // place records sorted-by-bucket into LDS
        #pragma unroll
        for (int k = 0; k < EPT; ++k) {
            if (bb[k] >= 0) {
                const int p = lof[bb[k]] + atomicAdd(&lh[bb[k]], 1);
                srec[p] = rec[k];
                sbkt[p] = (unsigned short)bb[k];
            }
        }
        __syncthreads();

        // stream out: consecutive lanes -> consecutive addresses per run
        const int total = min(256 * EPT, E - base);
        for (int i = tid; i < total; i += 256) {
            const int bkt  = sbkt[i];
            const int gidx = gbase[bkt] + i;
            if (gidx < (bkt + 1) * CAP)           // 11-sigma overflow guard
                g.bin[gidx] = srec[i];
        }
        return;
    }

    // ---------------- gemm32 path: [u|v] = x @ Wc1; u += b1 ----------------
    constexpr int K = 32;
    const int lane = threadIdx.x & 63;
    const int m    = lane & 15;                // A row / D col-lane
    const int quad = lane >> 4;
    const int bx   = blockIdx.x - bBlk;
    const int wid  = (bx * 256 + threadIdx.x) >> 6;
    const int nW   = ((gridDim.x - bBlk) * 256) >> 6;

    half8 bf[8];                               // B[k=quad*8+j][n=16t+m]
    #pragma unroll
    for (int t = 0; t < 8; ++t)
        #pragma unroll
        for (int j = 0; j < 8; ++j)
            bf[t][j] = Wc[(quad * 8 + j) * 128 + t * 16 + m];

    float bv[4];
    #pragma unroll
    for (int t = 0; t < 4; ++t) bv[t] = bias[t * 16 + m];

    const int tiles = (N + 15) / 16;
    for (int tile = wid; tile < tiles; tile += nW) {
        const int nbase = tile * 16;
        const int nodeA = min(nbase + m, N - 1);
        const float4* rp = (const float4*)(g.x + (size_t)nodeA * K);

        half8 a;
        {
            const float4 f0 = rp[quad * 2];
            const float4 f1 = rp[quad * 2 + 1];
            a[0] = (_Float16)f0.x; a[1] = (_Float16)f0.y;
            a[2] = (_Float16)f0.z; a[3] = (_Float16)f0.w;
            a[4] = (_Float16)f1.x; a[5] = (_Float16)f1.y;
            a[6] = (_Float16)f1.z; a[7] = (_Float16)f1.w;
        }

        f32x4 acc[8];
        #pragma unroll
        for (int t = 0; t < 8; ++t) {
            acc[t] = (f32x4){0.f, 0.f, 0.f, 0.f};
            acc[t] = __builtin_amdgcn_mfma_f32_16x16x32_f16(
                a, bf[t], acc[t], 0, 0, 0);
        }

        #pragma unroll
        for (int r = 0; r < 4; ++r) {          // D[m=quad*4+r][n=lane&15]
            const int node = nbase + quad * 4 + r;
            if (node < N) {
                float* urow = g.u + (size_t)node * HID;
                #pragma unroll
                for (int t = 0; t < 4; ++t)
                    urow[t * 16 + m] = acc[t][r] + bv[t];
                const unsigned int e0 = f2hbits(acc[4][r]);   // channel m
                const unsigned int e1 = f2hbits(acc[5][r]);   // channel m+16
                const unsigned int e2 = f2hbits(acc[6][r]);   // channel m+32
                const unsigned int e3 = f2hbits(acc[7][r]);   // channel m+48
                uint2 pack;
                pack.x = (e1 << 16) | e0;
                pack.y = (e3 << 16) | e2;
                ((uint2*)(g.vk + (size_t)node * HID))[m] = pack;
            }
        }
    }
}

// ---- MFMA node GEMM layer 2: input = g.h fp16 row-major ----
__global__ __launch_bounds__(256) void gemm64_kernel(
    G g0, G g1, const _Float16* __restrict__ Wc,
    const float* __restrict__ bias, int N)
{
    const G g = blockIdx.y ? g1 : g0;
    constexpr int K = 64, KH = 2;
    const int lane = threadIdx.x & 63;
    const int m    = lane & 15;
    const int quad = lane >> 4;
    const int wid  = (blockIdx.x * 256 + threadIdx.x) >> 6;
    const int nW   = (gridDim.x * 256) >> 6;

    half8 bf[8][KH];
    #pragma unroll
    for (int t = 0; t < 8; ++t)
        #pragma unroll
        for (int hh = 0; hh < KH; ++hh)
            #pragma unroll
            for (int j = 0; j < 8; ++j)
                bf[t][hh][j] = Wc[(hh * 32 + quad * 8 + j) * 128 + t * 16 + m];

    float bv[4];
    #pragma unroll
    for (int t = 0; t < 4; ++t) bv[t] = bias[t * 16 + m];

    const int tiles = (N + 15) / 16;
    for (int tile = wid; tile < tiles; tile += nW) {
        const int nbase = tile * 16;
        const int nodeA = min(nbase + m, N - 1);
        const half8* rp = (const half8*)(g.h + (size_t)nodeA * K);

        half8 a[KH];
        #pragma unroll
        for (int hh = 0; hh < KH; ++hh) a[hh] = rp[hh * 4 + quad];

        f32x4 acc[8];
        #pragma unroll
        for (int t = 0; t < 8; ++t) {
            acc[t] = (f32x4){0.f, 0.f, 0.f, 0.f};
            #pragma unroll
            for (int hh = 0; hh < KH; ++hh)
                acc[t] = __builtin_amdgcn_mfma_f32_16x16x32_f16(
                    a[hh], bf[t][hh], acc[t], 0, 0, 0);
        }

        #pragma unroll
        for (int r = 0; r < 4; ++r) {          // D[m=quad*4+r][n=lane&15]
            const int node = nbase + quad * 4 + r;
            if (node < N) {
                float* urow = g.u + (size_t)node * HID;
                #pragma unroll
                for (int t = 0; t < 4; ++t)
                    urow[t * 16 + m] = acc[t][r] + bv[t];
                const unsigned int e0 = f2hbits(acc[4][r]);
                const unsigned int e1 = f2hbits(acc[5][r]);
                const unsigned int e2 = f2hbits(acc[6][r]);
                const unsigned int e3 = f2hbits(acc[7][r]);
                uint2 pack;
                pack.x = (e1 << 16) | e0;
                pack.y = (e3 << 16) | e2;
                ((uint2*)(g.vk + (size_t)node * HID))[m] = pack;
            }
        }
    }
}

// ---- aggregate: 256 threads per 64-node bucket, SINGLE scan ----
// Phase A: coalesced record read + LDS counting sort into per-node lists,
//   padded to multiples of 8 with sentinel src=N (-inf vk row).
// Phase B: 32 groups x 8 lanes, 2 sequential nodes/group; full-row uint4
//   gathers (8 rows per wave-instruction); 2-stage ping-pong pipeline keeps
//   16 gathers in flight (chunk c+1 issued before chunk c's pkmax chain).
// OUT16=true (layer 1): write h fp16 row-major.  false: write fp32 out.
template<bool OUT16>
__global__ __launch_bounds__(256) void agg_kernel(G g0, G g1, int N, int NB, int two) {
    int b, gi;
    if (two) {                       // XCD partition: bid%8 -> XCD (heuristic)
        const int bid = blockIdx.x;
        const int xcd = bid & 7;
        gi = xcd >> 2;               // XCD 0-3: graph 0, XCD 4-7: graph 1
        b  = (bid >> 3) * 4 + (xcd & 3);
    } else { gi = 0; b = blockIdx.x; }
    if (b >= NB) return;
    const G g = gi ? g1 : g0;

    __shared__ int lcnt[TILE];
    __shared__ alignas(16) unsigned short lrec[TILE][CAPN];  // 12.3 KB
    for (int i = threadIdx.x; i < TILE; i += 256) lcnt[i] = 0;
    __syncthreads();

    const int cnt = min(g.bcnt[b], CAP);
    const unsigned int* __restrict__ bp = g.bin + (size_t)b * CAP;
    for (int i = threadIdx.x; i < cnt; i += 256) {
        const unsigned int rec = bp[i];
        const int d = rec & (TILE - 1);
        const int p = atomicAdd(&lcnt[d], 1);
        if (p < CAPN) lrec[d][p] = (unsigned short)(rec >> TSH);
    }
    __syncthreads();
    for (int t = threadIdx.x; t < TILE; t += 256) {   // pad to x8 w/ sentinel
        const int c  = min(lcnt[t], CAPN);
        const int cp = (c + 7) & ~7;
        for (int p = c; p < cp; ++p) lrec[t][p] = (unsigned short)N;
        lcnt[t] = cp;
    }
    __syncthreads();

    const int grp = threadIdx.x >> 3;        // 32 groups of 8 lanes
    const int sub = threadIdx.x & 7;
    const uint4* __restrict__ vk4 = (const uint4*)g.vk;   // 8 uint4 per row

    #pragma unroll
    for (int i = 0; i < 2; ++i) {
        const int nl = grp + 32 * i;
        const int n  = b * TILE + nl;
        if (n >= N) continue;
        const int cp = lcnt[nl];

        // lane sub covers uint slots 4sub..4sub+3:
        //   m0: ch {2sub, 2sub+16}   m1: ch {2sub+32, 2sub+48}
        //   m2: ch {2sub+1, 2sub+17} m3: ch {2sub+33, 2sub+49}
        unsigned int m0 = 0xFC00FC00u, m1 = m0, m2 = m0, m3 = m0;

        uint4 aA[8], aB[8];
#define GATHER(BUF, J)                                                    \
        {                                                                 \
            const uint4 rq = *(const uint4*)(&lrec[nl][(J)]);             \
            BUF[0] = vk4[(size_t)(rq.x & 0xFFFFu) * 8 + sub];             \
            BUF[1] = vk4[(size_t)(rq.x >> 16)     * 8 + sub];             \
            BUF[2] = vk4[(size_t)(rq.y & 0xFFFFu) * 8 + sub];             \
            BUF[3] = vk4[(size_t)(rq.y >> 16)     * 8 + sub];             \
            BUF[4] = vk4[(size_t)(rq.z & 0xFFFFu) * 8 + sub];             \
            BUF[5] = vk4[(size_t)(rq.z >> 16)     * 8 + sub];             \
            BUF[6] = vk4[(size_t)(rq.w & 0xFFFFu) * 8 + sub];             \
            BUF[7] = vk4[(size_t)(rq.w >> 16)     * 8 + sub];             \
        }
#define CONSUME(BUF)                                                      \
        _Pragma("unroll")                                                 \
        for (int k = 0; k < 8; ++k) {                                     \
            m0 = pkmax(m0, BUF[k].x);                                     \
            m1 = pkmax(m1, BUF[k].y);                                     \
            m2 = pkmax(m2, BUF[k].z);                                     \
            m3 = pkmax(m3, BUF[k].w);                                     \
        }

        const int nc = cp >> 3;                  // 8-record chunks
        if (nc > 0) {
            GATHER(aA, 0)
            int c = 0;
            for (; c + 2 <= nc; c += 2) {        // steady state: 16 in flight
                GATHER(aB, (c + 1) * 8)
                CONSUME(aA)
                if (c + 2 < nc) GATHER(aA, (c + 2) * 8)
                CONSUME(aB)
            }
            if (c < nc) CONSUME(aA)              // odd-chunk tail
        }
#undef GATHER
#undef CONSUME

        const bool has = cp > 0;
        const float2* __restrict__ u2 =
            (const float2*)(g.u + (size_t)n * HID);      // pair {2sub,2sub+1}
        const float2 ua = u2[sub], ub = u2[sub + 8],
                     uc = u2[sub + 16], ud = u2[sub + 24];
        float r0, r1, r2, r3, r4, r5, r6, r7;
        r0 = has ? fmaxf(ua.x + h2f(m0 & 0xFFFFu), 0.f) : 0.f;  // ch 2sub
        r1 = has ? fmaxf(ua.y + h2f(m2 & 0xFFFFu), 0.f) : 0.f;  // ch 2sub+1
        r2 = has ? fmaxf(ub.x + h2f(m0 >> 16),     0.f) : 0.f;  // +16
        r3 = has ? fmaxf(ub.y + h2f(m2 >> 16),     0.f) : 0.f;
        r4 = has ? fmaxf(uc.x + h2f(m1 & 0xFFFFu), 0.f) : 0.f;  // +32
        r5 = has ? fmaxf(uc.y + h2f(m3 & 0xFFFFu), 0.f) : 0.f;
        r6 = has ? fmaxf(ud.x + h2f(m1 >> 16),     0.f) : 0.f;  // +48
        r7 = has ? fmaxf(ud.y + h2f(m3 >> 16),     0.f) : 0.f;
        if constexpr (OUT16) {       // fp16 h, same rounding gemm64 would do
            unsigned int* hrow = (unsigned int*)(g.h + (size_t)n * HID);
            hrow[sub]      = (unsigned int)f2hbits(r0) | ((unsigned int)f2hbits(r1) << 16);
            hrow[sub + 8]  = (unsigned int)f2hbits(r2) | ((unsigned int)f2hbits(r3) << 16);
            hrow[sub + 16] = (unsigned int)f2hbits(r4) | ((unsigned int)f2hbits(r5) << 16);
            hrow[sub + 24] = (unsigned int)f2hbits(r6) | ((unsigned int)f2hbits(r7) << 16);
        } else {
            float2* orow = (float2*)(g.out + (size_t)n * HID);
            orow[sub]      = (float2){r0, r1};
            orow[sub + 8]  = (float2){r2, r3};
            orow[sub + 16] = (float2){r4, r5};
            orow[sub + 24] = (float2){r6, r7};
        }
    }
}

// ---------------- orchestration ----------------

extern "C" void kernel_launch(void* const* d_in, const int* in_sizes, int n_in,
                              void* d_out, int out_size, void* d_ws, size_t ws_size,
                              hipStream_t stream) {
    const float* x1  = (const float*)d_in[0];
    const int*   ei1 = (const int*)d_in[1];   // [2,E]: src row then dst row
    const float* x2  = (const float*)d_in[2];
    const int*   ei2 = (const int*)d_in[3];
    const float* W1  = (const float*)d_in[4];
    const float* b1  = (const float*)d_in[5];
    // d_in[6] = prelu_a: unused (identity on >=0)
    const float* W2  = (const float*)d_in[7];
    const float* b2  = (const float*)d_in[8];

    const int N  = in_sizes[0] / 32;
    const int E  = in_sizes[1] / 2;
    const int NB = (N + TILE - 1) / TILE;     // 782 for N=50000
    float* out = (float*)d_out;

    const size_t rowB = (size_t)N * HID * sizeof(float);            // 12.8 MB
    const size_t vkB  = ((size_t)(N + 1) * HID * 2 + 63) & ~(size_t)63;
    const size_t hB   = ((size_t)N * HID * 2 + 63) & ~(size_t)63;   //  6.4 MB
    const size_t binB = ((size_t)NB * CAP * sizeof(int) + 63) & ~(size_t)63;
    const size_t nbB  = ((size_t)(NB + 2) * sizeof(int) + 63) & ~(size_t)63;
    const size_t wc1B = ((size_t)32 * 128 * 2 + 63) & ~(size_t)63;
    const size_t wc2B = ((size_t)64 * 128 * 2 + 63) & ~(size_t)63;

    const int bBlk = (E + 256 * EPT - 1) / (256 * EPT);   // 391 per graph
    const int gBlk = 512;
    const int pBlk = (32 * 64 + 64 * 64 + 2 * HID + 255) / 256;
    const int aggBlk2 = ((NB + 3) / 4) * 8;   // XCD-partitioned 1D grid
    const int aggBlk1 = NB;

    _Float16* wc1 = nullptr;
    _Float16* wc2 = nullptr;

    auto run = [&](G ga, G gb, int ny) {
        // bcnt arrays contiguous across graphs: one memset when ny==2
        hipMemsetAsync(ga.bcnt, 0, (size_t)ny * nbB, stream);
        bin_gemm32_kernel<<<dim3(bBlk + gBlk, ny), 256, 0, stream>>>(
            ga, gb, E, NB, N, wc1, b1, bBlk);
        if (ny == 2) agg_kernel<true><<<aggBlk2, 256, 0, stream>>>(ga, gb, N, NB, 1);
        else         agg_kernel<true><<<aggBlk1, 256, 0, stream>>>(ga, ga, N, NB, 0);
        gemm64_kernel<<<dim3(gBlk, ny), 256, 0, stream>>>(ga, gb, wc2, b2, N);
        if (ny == 2) agg_kernel<false><<<aggBlk2, 256, 0, stream>>>(ga, gb, N, NB, 1);
        else         agg_kernel<false><<<aggBlk1, 256, 0, stream>>>(ga, ga, N, NB, 0);
    };

    char* ws = (char*)d_ws;
    const size_t needBoth =
        2 * rowB + 2 * binB + 2 * vkB + 2 * hB + wc1B + wc2B + 2 * nbB;

    if (ws_size >= needBoth) {
        float* u0 = (float*)ws;                  ws += rowB;
        float* u1 = (float*)ws;                  ws += rowB;
        unsigned int* bin0 = (unsigned int*)ws;  ws += binB;
        unsigned int* bin1 = (unsigned int*)ws;  ws += binB;
        unsigned short* vk0 = (unsigned short*)ws;  ws += vkB;
        unsigned short* vk1 = (unsigned short*)ws;  ws += vkB;
        _Float16* h0 = (_Float16*)ws;            ws += hB;
        _Float16* h1 = (_Float16*)ws;            ws += hB;
        wc1 = (_Float16*)ws;                     ws += wc1B;
        wc2 = (_Float16*)ws;                     ws += wc2B;
        int* bcnt0 = (int*)ws;                   ws += nbB;
        int* bcnt1 = (int*)ws;                   // contiguous with bcnt0

        G g0{x1, ei1, ei1 + E, bcnt0, bin0, u0, vk0, h0, out};
        G g1{x2, ei2, ei2 + E, bcnt1, bin1, u1, vk1, h1, out + (size_t)N * HID};
        prep_w_kernel<<<pBlk, 256, 0, stream>>>(W1, W2, wc1, wc2, vk0, vk1, N);
        run(g0, g1, 2);
    } else {
        // sequential fallback (~34 MB): one graph's buffers, reused
        float* u = (float*)ws;                   ws += rowB;
        unsigned int* bin = (unsigned int*)ws;   ws += binB;
        unsigned short* vk = (unsigned short*)ws;  ws += vkB;
        _Float16* h = (_Float16*)ws;             ws += hB;
        wc1 = (_Float16*)ws;                     ws += wc1B;
        wc2 = (_Float16*)ws;                     ws += wc2B;
        int* bcnt = (int*)ws;

        prep_w_kernel<<<pBlk, 256, 0, stream>>>(W1, W2, wc1, wc2, vk, vk, N);
        for (int g = 0; g < 2; ++g) {
            const int* ei = g ? ei2 : ei1;
            G gp{g ? x2 : x1, ei, ei + E, bcnt, bin,
                 u, vk, h, out + (size_t)g * N * HID};
            run(gp, gp, 1);
        }
    }
}